// Round 5
// baseline (2228.148 us; speedup 1.0000x reference)
//
#include <hip/hip_runtime.h>
#include <math.h>

#define DFEAT 64
#define BUCKET_SHIFT 8          // 256 nodes per bucket
#define BSZ (1 << BUCKET_SHIFT)
#define NB_MAX 512              // supports N <= 131072
#define PART_BLOCKS 192

static inline int imin(int a, int b) { return a < b ? a : b; }

// ---------------- preprocessing ----------------

__global__ void k_zero_i32(int* __restrict__ p, int n) {
  int i = blockIdx.x * blockDim.x + threadIdx.x;
  int stride = gridDim.x * blockDim.x;
  for (; i < n; i += stride) p[i] = 0;
}

// bucket histograms for dst and src (LDS-only per-edge atomics; global adds are
// 2*NB ints per block -> L2-hot, no scattered traffic)
__global__ void __launch_bounds__(256) k_hist(
    const int* __restrict__ src, const int* __restrict__ dst,
    int* __restrict__ dst_cnt, int* __restrict__ src_cnt, int E, int NB) {
  __shared__ int hd[NB_MAX], hs[NB_MAX];
  for (int b = threadIdx.x; b < NB; b += blockDim.x) { hd[b] = 0; hs[b] = 0; }
  __syncthreads();
  int i = blockIdx.x * blockDim.x + threadIdx.x;
  int stride = gridDim.x * blockDim.x;
  for (; i < E; i += stride) {
    atomicAdd(&hd[dst[i] >> BUCKET_SHIFT], 1);
    atomicAdd(&hs[src[i] >> BUCKET_SHIFT], 1);
  }
  __syncthreads();
  for (int b = threadIdx.x; b < NB; b += blockDim.x) {
    if (hd[b]) atomicAdd(&dst_cnt[b], hd[b]);
    if (hs[b]) atomicAdd(&src_cnt[b], hs[b]);
  }
}

// exclusive scans of both bucket-count arrays -> base (NB+1) and live cursors
__global__ void k_scan2(const int* __restrict__ dst_cnt, const int* __restrict__ src_cnt,
                        int* __restrict__ dst_base, int* __restrict__ src_base,
                        int* __restrict__ dst_cur, int* __restrict__ src_cur,
                        int NB, int E) {
  __shared__ int sh[NB_MAX];
  int t = threadIdx.x;
  int v = (t < NB) ? dst_cnt[t] : 0;
  sh[t] = v;
  __syncthreads();
  for (int o = 1; o < NB_MAX; o <<= 1) {
    int x = (t >= o) ? sh[t - o] : 0;
    __syncthreads();
    sh[t] += x;
    __syncthreads();
  }
  if (t < NB) { dst_base[t] = sh[t] - v; dst_cur[t] = sh[t] - v; }
  if (t == 0) dst_base[NB] = E;
  __syncthreads();
  int v2 = (t < NB) ? src_cnt[t] : 0;
  sh[t] = v2;
  __syncthreads();
  for (int o = 1; o < NB_MAX; o <<= 1) {
    int x = (t >= o) ? sh[t - o] : 0;
    __syncthreads();
    sh[t] += x;
    __syncthreads();
  }
  if (t < NB) { src_base[t] = sh[t] - v2; src_cur[t] = sh[t] - v2; }
  if (t == 0) src_base[NB] = E;
}

// coarse partition: (dloc<<24|src) pairs grouped by dst bucket (4B/edge) and a
// 1B/edge src-local stream grouped by src bucket. One reservation atomic per
// (block,bucket) -> writes are contiguous runs.
__global__ void __launch_bounds__(256) k_partition(
    const int* __restrict__ src, const int* __restrict__ dst,
    int* __restrict__ dst_cur, int* __restrict__ src_cur,
    unsigned* __restrict__ pairs, unsigned char* __restrict__ sloc, int E, int NB) {
  __shared__ int cd[NB_MAX], cs[NB_MAX];
  const int per = (E + gridDim.x - 1) / gridDim.x;
  int e0 = blockIdx.x * per;
  int e1 = e0 + per; if (e1 > E) e1 = E;
  for (int b = threadIdx.x; b < NB; b += blockDim.x) { cd[b] = 0; cs[b] = 0; }
  __syncthreads();
  for (int i = e0 + threadIdx.x; i < e1; i += blockDim.x) {
    atomicAdd(&cd[dst[i] >> BUCKET_SHIFT], 1);
    atomicAdd(&cs[src[i] >> BUCKET_SHIFT], 1);
  }
  __syncthreads();
  for (int b = threadIdx.x; b < NB; b += blockDim.x) {
    int c = cd[b]; cd[b] = c ? atomicAdd(&dst_cur[b], c) : 0;
    int c2 = cs[b]; cs[b] = c2 ? atomicAdd(&src_cur[b], c2) : 0;
  }
  __syncthreads();
  for (int i = e0 + threadIdx.x; i < e1; i += blockDim.x) {
    int d = dst[i], s = src[i];
    int p = atomicAdd(&cd[d >> BUCKET_SHIFT], 1);
    pairs[p] = ((unsigned)(d & (BSZ - 1)) << 24) | (unsigned)s;
    int q = atomicAdd(&cs[s >> BUCKET_SHIFT], 1);
    sloc[q] = (unsigned char)(s & (BSZ - 1));
  }
}

// one block per dst bucket: LDS in-degree count + scan -> row_off, ndst, and the
// csr_src fill (scatter confined to this bucket's L2-hot window).
__global__ void __launch_bounds__(256) k_build_dst(
    const unsigned* __restrict__ pairs, const int* __restrict__ dst_base,
    int* __restrict__ row_off, float* __restrict__ ndst, int* __restrict__ csr_src,
    int N, int E) {
  __shared__ int cnt[BSZ];
  __shared__ int pos[BSZ];
  int b = blockIdx.x, t = threadIdx.x;
  int s0 = dst_base[b], s1 = dst_base[b + 1];
  cnt[t] = 0;
  __syncthreads();
  for (int i = s0 + t; i < s1; i += BSZ) atomicAdd(&cnt[pairs[i] >> 24], 1);
  __syncthreads();
  int c = cnt[t];
  pos[t] = c;
  __syncthreads();
  for (int o = 1; o < BSZ; o <<= 1) {
    int x = (t >= o) ? pos[t - o] : 0;
    __syncthreads();
    pos[t] += x;
    __syncthreads();
  }
  int excl = pos[t] - c;
  int node = (b << BUCKET_SHIFT) + t;
  if (node < N) {
    row_off[node] = s0 + excl;
    ndst[node] = c > 0 ? rsqrtf((float)c) : 0.0f;
  }
  __syncthreads();
  pos[t] = excl;  // live cursors
  __syncthreads();
  for (int i = s0 + t; i < s1; i += BSZ) {
    unsigned pr = pairs[i];
    int p = atomicAdd(&pos[pr >> 24], 1);
    csr_src[s0 + p] = (int)(pr & 0xFFFFFFu);
  }
  if (b == 0 && t == 0) row_off[N] = E;
}

// one block per src bucket: LDS out-degree count -> nsrc (dense write)
__global__ void __launch_bounds__(256) k_build_src(
    const unsigned char* __restrict__ sloc, const int* __restrict__ src_base,
    float* __restrict__ nsrc, int N) {
  __shared__ int cnt[BSZ];
  int b = blockIdx.x, t = threadIdx.x;
  int s0 = src_base[b], s1 = src_base[b + 1];
  cnt[t] = 0;
  __syncthreads();
  for (int i = s0 + t; i < s1; i += BSZ) atomicAdd(&cnt[sloc[i]], 1);
  __syncthreads();
  int node = (b << BUCKET_SHIFT) + t;
  if (node < N) nsrc[node] = cnt[t] > 0 ? rsqrtf((float)cnt[t]) : 0.0f;
}

// A[i] = x[i] * nsrc[row]   (float4-vectorized; nq = N*16 quads)
__global__ void __launch_bounds__(256) k_prescale(const float* __restrict__ x,
                                                  const float* __restrict__ nsrc,
                                                  float* __restrict__ A, int nq) {
  int i = blockIdx.x * blockDim.x + threadIdx.x;
  int stride = gridDim.x * blockDim.x;
  for (; i < nq; i += stride) {
    int row = i >> 4;
    float4 v = ((const float4*)x)[i];
    float s = nsrc[row];
    v.x *= s; v.y *= s; v.z *= s; v.w *= s;
    ((float4*)A)[i] = v;
  }
}

// ---------------- fused layer kernel ----------------
// 4 rows per wave: 16-lane group g owns row r4+g, lane's quad = 4*(lane&15).
// Gather: per edge all 16 lanes of the group read the src row (256B coalesced);
// each lane issues up to 4 independent float4 loads per unrolled step and every
// edge is independent -> deep MLP. GEMM: 4 rows sequentially, a[j] broadcast by
// constant-lane shfl (readlane) from owner lane g*16 + j/4, W column in regs.
__global__ void __launch_bounds__(256, 4) k_layer(
    const float* __restrict__ hin, const float* __restrict__ ndst,
    const float* __restrict__ nsrc, const int* __restrict__ row_off,
    const int* __restrict__ csr_src, const float* __restrict__ W,
    const float* __restrict__ b, float* __restrict__ hout, int n, int scale_out) {
  const int lane = threadIdx.x & 63;
  const int g = lane >> 4;         // row slot 0..3
  const int q4 = (lane & 15) * 4;  // feature quad offset

  float wreg[DFEAT];
#pragma unroll
  for (int k = 0; k < DFEAT; k++) wreg[k] = W[k * DFEAT + lane];
  const float bias = b[lane];

  int wid = blockIdx.x * (blockDim.x >> 6) + (threadIdx.x >> 6);
  int nw = gridDim.x * (blockDim.x >> 6);

  for (int r4 = wid * 4; r4 < n; r4 += nw * 4) {
    int r = r4 + g;
    bool act = r < n;
    int beg = act ? row_off[r] : 0;
    int end = act ? row_off[r + 1] : 0;
    float ax0 = 0, ay0 = 0, az0 = 0, aw0 = 0;
    float ax1 = 0, ay1 = 0, az1 = 0, aw1 = 0;
    float ax2 = 0, ay2 = 0, az2 = 0, aw2 = 0;
    float ax3 = 0, ay3 = 0, az3 = 0, aw3 = 0;
    int k = beg;
    for (; k + 4 <= end; k += 4) {
      int sA = csr_src[k], sB = csr_src[k + 1], sC = csr_src[k + 2], sD = csr_src[k + 3];
      const float4 vA = *(const float4*)(hin + sA * DFEAT + q4);
      const float4 vB = *(const float4*)(hin + sB * DFEAT + q4);
      const float4 vC = *(const float4*)(hin + sC * DFEAT + q4);
      const float4 vD = *(const float4*)(hin + sD * DFEAT + q4);
      ax0 += vA.x; ay0 += vA.y; az0 += vA.z; aw0 += vA.w;
      ax1 += vB.x; ay1 += vB.y; az1 += vB.z; aw1 += vB.w;
      ax2 += vC.x; ay2 += vC.y; az2 += vC.z; aw2 += vC.w;
      ax3 += vD.x; ay3 += vD.y; az3 += vD.z; aw3 += vD.w;
    }
    for (; k < end; k++) {
      int sA = csr_src[k];
      const float4 vA = *(const float4*)(hin + sA * DFEAT + q4);
      ax0 += vA.x; ay0 += vA.y; az0 += vA.z; aw0 += vA.w;
    }
    float sx = (ax0 + ax1) + (ax2 + ax3);
    float sy = (ay0 + ay1) + (ay2 + ay3);
    float sz = (az0 + az1) + (az2 + az3);
    float sw = (aw0 + aw1) + (aw2 + aw3);
    float nd = act ? ndst[r] : 0.0f;
    sx *= nd; sy *= nd; sz *= nd; sw *= nd;

    // GEMM: 4 rows, constant-lane broadcasts, 4 independent FMA chains
    float o0 = bias, o1 = bias, o2 = bias, o3 = bias;
#pragma unroll
    for (int j4 = 0; j4 < 16; j4++) {
      o0 = fmaf(__shfl(sx, j4),      wreg[4 * j4 + 0], o0);
      o0 = fmaf(__shfl(sy, j4),      wreg[4 * j4 + 1], o0);
      o0 = fmaf(__shfl(sz, j4),      wreg[4 * j4 + 2], o0);
      o0 = fmaf(__shfl(sw, j4),      wreg[4 * j4 + 3], o0);
      o1 = fmaf(__shfl(sx, 16 + j4), wreg[4 * j4 + 0], o1);
      o1 = fmaf(__shfl(sy, 16 + j4), wreg[4 * j4 + 1], o1);
      o1 = fmaf(__shfl(sz, 16 + j4), wreg[4 * j4 + 2], o1);
      o1 = fmaf(__shfl(sw, 16 + j4), wreg[4 * j4 + 3], o1);
      o2 = fmaf(__shfl(sx, 32 + j4), wreg[4 * j4 + 0], o2);
      o2 = fmaf(__shfl(sy, 32 + j4), wreg[4 * j4 + 1], o2);
      o2 = fmaf(__shfl(sz, 32 + j4), wreg[4 * j4 + 2], o2);
      o2 = fmaf(__shfl(sw, 32 + j4), wreg[4 * j4 + 3], o2);
      o3 = fmaf(__shfl(sx, 48 + j4), wreg[4 * j4 + 0], o3);
      o3 = fmaf(__shfl(sy, 48 + j4), wreg[4 * j4 + 1], o3);
      o3 = fmaf(__shfl(sz, 48 + j4), wreg[4 * j4 + 2], o3);
      o3 = fmaf(__shfl(sw, 48 + j4), wreg[4 * j4 + 3], o3);
    }
    if (r4 + 0 < n) {
      float v = fmaxf(o0, 0.0f);
      if (scale_out) v *= nsrc[r4 + 0];
      hout[(r4 + 0) * DFEAT + lane] = v;
    }
    if (r4 + 1 < n) {
      float v = fmaxf(o1, 0.0f);
      if (scale_out) v *= nsrc[r4 + 1];
      hout[(r4 + 1) * DFEAT + lane] = v;
    }
    if (r4 + 2 < n) {
      float v = fmaxf(o2, 0.0f);
      if (scale_out) v *= nsrc[r4 + 2];
      hout[(r4 + 2) * DFEAT + lane] = v;
    }
    if (r4 + 3 < n) {
      float v = fmaxf(o3, 0.0f);
      if (scale_out) v *= nsrc[r4 + 3];
      hout[(r4 + 3) * DFEAT + lane] = v;
    }
  }
}

// ---------------- launch ----------------

extern "C" void kernel_launch(void* const* d_in, const int* in_sizes, int n_in,
                              void* d_out, int out_size, void* d_ws, size_t ws_size,
                              hipStream_t stream) {
  const float* x = (const float*)d_in[0];
  const int* ei = (const int*)d_in[1];
  const float* Ws = (const float*)d_in[2];
  const float* bs = (const float*)d_in[3];
  float* out = (float*)d_out;

  const int N = in_sizes[0] / DFEAT;
  const int E = in_sizes[1] / 2;
  const int L = in_sizes[2] / (DFEAT * DFEAT);
  const int* src = ei;
  const int* dst = ei + E;
  const int NB = (N + BSZ - 1) >> BUCKET_SHIFT;  // 391 for N=100K

  // workspace carve-up (256B-aligned)
  char* w = (char*)d_ws;
  auto alloc = [&](size_t bytes) -> void* {
    void* p = (void*)w;
    w += (bytes + 255) & ~(size_t)255;
    return p;
  };
  int* cnts = (int*)alloc(sizeof(int) * 2 * NB_MAX);       // dst_cnt | src_cnt
  int* dst_cnt = cnts;
  int* src_cnt = cnts + NB_MAX;
  int* dst_base = (int*)alloc(sizeof(int) * (NB_MAX + 1));
  int* src_base = (int*)alloc(sizeof(int) * (NB_MAX + 1));
  int* dst_cur = (int*)alloc(sizeof(int) * NB_MAX);
  int* src_cur = (int*)alloc(sizeof(int) * NB_MAX);
  float* nsrc = (float*)alloc(sizeof(float) * N);
  float* ndst = (float*)alloc(sizeof(float) * N);
  int* row_off = (int*)alloc(sizeof(int) * (N + 1));
  int* csr_src = (int*)alloc(sizeof(int) * E);
  float* A = (float*)alloc(sizeof(float) * N * DFEAT);
  float* B = (float*)alloc(sizeof(float) * N * DFEAT);
  // aliases into B (dead before layer0 writes B):
  unsigned* pairs = (unsigned*)B;                          // 4B * E = 6.4MB
  unsigned char* sloc = (unsigned char*)B + (16u << 20);   // 1B * E at +16MB
  (void)ws_size; (void)n_in; (void)out_size;

  k_zero_i32<<<4, 256, 0, stream>>>(cnts, 2 * NB_MAX);
  k_hist<<<512, 256, 0, stream>>>(src, dst, dst_cnt, src_cnt, E, NB);
  k_scan2<<<1, NB_MAX, 0, stream>>>(dst_cnt, src_cnt, dst_base, src_base,
                                    dst_cur, src_cur, NB, E);
  k_partition<<<PART_BLOCKS, 256, 0, stream>>>(src, dst, dst_cur, src_cur,
                                               pairs, sloc, E, NB);
  k_build_dst<<<NB, BSZ, 0, stream>>>(pairs, dst_base, row_off, ndst, csr_src, N, E);
  k_build_src<<<NB, BSZ, 0, stream>>>(sloc, src_base, nsrc, N);
  k_prescale<<<2048, 256, 0, stream>>>(x, nsrc, A, N * (DFEAT / 4));

  // layer chain: A -> B -> A -> out (gather must not alias its output)
  for (int l = 0; l < L; l++) {
    const float* hin = (l == 0) ? A : ((l & 1) ? B : A);
    float* hout = (l == L - 1) ? out : ((l & 1) ? A : B);
    k_layer<<<2048, 256, 0, stream>>>(hin, ndst, nsrc, row_off, csr_src,
                                      Ws + l * DFEAT * DFEAT, bs + l * DFEAT,
                                      hout, N, l != L - 1);
  }
}

// Round 6
// 595.440 us; speedup vs baseline: 3.7420x; 3.7420x over previous
//
#include <hip/hip_runtime.h>
#include <math.h>

#define DFEAT 64
#define BUCKET_SHIFT 8          // 256 nodes per bucket
#define BSZ (1 << BUCKET_SHIFT)
#define NB_MAX 512              // supports N <= 131072
#define PART_BLOCKS 192

static inline int imin(int a, int b) { return a < b ? a : b; }

// ---------------- preprocessing ----------------

__global__ void k_zero_i32(int* __restrict__ p, int n) {
  int i = blockIdx.x * blockDim.x + threadIdx.x;
  int stride = gridDim.x * blockDim.x;
  for (; i < n; i += stride) p[i] = 0;
}

// bucket histograms for dst and src (LDS-only per-edge atomics; global adds are
// 2*NB ints per block -> L2-hot, no scattered traffic)
__global__ void __launch_bounds__(256) k_hist(
    const int* __restrict__ src, const int* __restrict__ dst,
    int* __restrict__ dst_cnt, int* __restrict__ src_cnt, int E, int NB) {
  __shared__ int hd[NB_MAX], hs[NB_MAX];
  for (int b = threadIdx.x; b < NB; b += blockDim.x) { hd[b] = 0; hs[b] = 0; }
  __syncthreads();
  int i = blockIdx.x * blockDim.x + threadIdx.x;
  int stride = gridDim.x * blockDim.x;
  for (; i < E; i += stride) {
    atomicAdd(&hd[dst[i] >> BUCKET_SHIFT], 1);
    atomicAdd(&hs[src[i] >> BUCKET_SHIFT], 1);
  }
  __syncthreads();
  for (int b = threadIdx.x; b < NB; b += blockDim.x) {
    if (hd[b]) atomicAdd(&dst_cnt[b], hd[b]);
    if (hs[b]) atomicAdd(&src_cnt[b], hs[b]);
  }
}

// exclusive scans of both bucket-count arrays -> base (NB+1) and live cursors
__global__ void k_scan2(const int* __restrict__ dst_cnt, const int* __restrict__ src_cnt,
                        int* __restrict__ dst_base, int* __restrict__ src_base,
                        int* __restrict__ dst_cur, int* __restrict__ src_cur,
                        int NB, int E) {
  __shared__ int sh[NB_MAX];
  int t = threadIdx.x;
  int v = (t < NB) ? dst_cnt[t] : 0;
  sh[t] = v;
  __syncthreads();
  for (int o = 1; o < NB_MAX; o <<= 1) {
    int x = (t >= o) ? sh[t - o] : 0;
    __syncthreads();
    sh[t] += x;
    __syncthreads();
  }
  if (t < NB) { dst_base[t] = sh[t] - v; dst_cur[t] = sh[t] - v; }
  if (t == 0) dst_base[NB] = E;
  __syncthreads();
  int v2 = (t < NB) ? src_cnt[t] : 0;
  sh[t] = v2;
  __syncthreads();
  for (int o = 1; o < NB_MAX; o <<= 1) {
    int x = (t >= o) ? sh[t - o] : 0;
    __syncthreads();
    sh[t] += x;
    __syncthreads();
  }
  if (t < NB) { src_base[t] = sh[t] - v2; src_cur[t] = sh[t] - v2; }
  if (t == 0) src_base[NB] = E;
}

// coarse partition: (dloc<<24|src) pairs grouped by dst bucket (4B/edge) and a
// 1B/edge src-local stream grouped by src bucket. One reservation atomic per
// (block,bucket) -> writes are contiguous runs.
__global__ void __launch_bounds__(256) k_partition(
    const int* __restrict__ src, const int* __restrict__ dst,
    int* __restrict__ dst_cur, int* __restrict__ src_cur,
    unsigned* __restrict__ pairs, unsigned char* __restrict__ sloc, int E, int NB) {
  __shared__ int cd[NB_MAX], cs[NB_MAX];
  const int per = (E + gridDim.x - 1) / gridDim.x;
  int e0 = blockIdx.x * per;
  int e1 = e0 + per; if (e1 > E) e1 = E;
  for (int b = threadIdx.x; b < NB; b += blockDim.x) { cd[b] = 0; cs[b] = 0; }
  __syncthreads();
  for (int i = e0 + threadIdx.x; i < e1; i += blockDim.x) {
    atomicAdd(&cd[dst[i] >> BUCKET_SHIFT], 1);
    atomicAdd(&cs[src[i] >> BUCKET_SHIFT], 1);
  }
  __syncthreads();
  for (int b = threadIdx.x; b < NB; b += blockDim.x) {
    int c = cd[b]; cd[b] = c ? atomicAdd(&dst_cur[b], c) : 0;
    int c2 = cs[b]; cs[b] = c2 ? atomicAdd(&src_cur[b], c2) : 0;
  }
  __syncthreads();
  for (int i = e0 + threadIdx.x; i < e1; i += blockDim.x) {
    int d = dst[i], s = src[i];
    int p = atomicAdd(&cd[d >> BUCKET_SHIFT], 1);
    pairs[p] = ((unsigned)(d & (BSZ - 1)) << 24) | (unsigned)s;
    int q = atomicAdd(&cs[s >> BUCKET_SHIFT], 1);
    sloc[q] = (unsigned char)(s & (BSZ - 1));
  }
}

// one block per dst bucket: LDS in-degree count + scan -> row_off, ndst, and the
// csr_src fill (scatter confined to this bucket's L2-hot window).
__global__ void __launch_bounds__(256) k_build_dst(
    const unsigned* __restrict__ pairs, const int* __restrict__ dst_base,
    int* __restrict__ row_off, float* __restrict__ ndst, int* __restrict__ csr_src,
    int N, int E) {
  __shared__ int cnt[BSZ];
  __shared__ int pos[BSZ];
  int b = blockIdx.x, t = threadIdx.x;
  int s0 = dst_base[b], s1 = dst_base[b + 1];
  cnt[t] = 0;
  __syncthreads();
  for (int i = s0 + t; i < s1; i += BSZ) atomicAdd(&cnt[pairs[i] >> 24], 1);
  __syncthreads();
  int c = cnt[t];
  pos[t] = c;
  __syncthreads();
  for (int o = 1; o < BSZ; o <<= 1) {
    int x = (t >= o) ? pos[t - o] : 0;
    __syncthreads();
    pos[t] += x;
    __syncthreads();
  }
  int excl = pos[t] - c;
  int node = (b << BUCKET_SHIFT) + t;
  if (node < N) {
    row_off[node] = s0 + excl;
    ndst[node] = c > 0 ? rsqrtf((float)c) : 0.0f;
  }
  __syncthreads();
  pos[t] = excl;  // live cursors
  __syncthreads();
  for (int i = s0 + t; i < s1; i += BSZ) {
    unsigned pr = pairs[i];
    int p = atomicAdd(&pos[pr >> 24], 1);
    csr_src[s0 + p] = (int)(pr & 0xFFFFFFu);
  }
  if (b == 0 && t == 0) row_off[N] = E;
}

// one block per src bucket: LDS out-degree count -> nsrc (dense write)
__global__ void __launch_bounds__(256) k_build_src(
    const unsigned char* __restrict__ sloc, const int* __restrict__ src_base,
    float* __restrict__ nsrc, int N) {
  __shared__ int cnt[BSZ];
  int b = blockIdx.x, t = threadIdx.x;
  int s0 = src_base[b], s1 = src_base[b + 1];
  cnt[t] = 0;
  __syncthreads();
  for (int i = s0 + t; i < s1; i += BSZ) atomicAdd(&cnt[sloc[i]], 1);
  __syncthreads();
  int node = (b << BUCKET_SHIFT) + t;
  if (node < N) nsrc[node] = cnt[t] > 0 ? rsqrtf((float)cnt[t]) : 0.0f;
}

// A[i] = x[i] * nsrc[row]   (float4-vectorized; nq = N*16 quads)
__global__ void __launch_bounds__(256) k_prescale(const float* __restrict__ x,
                                                  const float* __restrict__ nsrc,
                                                  float* __restrict__ A, int nq) {
  int i = blockIdx.x * blockDim.x + threadIdx.x;
  int stride = gridDim.x * blockDim.x;
  for (; i < nq; i += stride) {
    int row = i >> 4;
    float4 v = ((const float4*)x)[i];
    float s = nsrc[row];
    v.x *= s; v.y *= s; v.z *= s; v.w *= s;
    ((float4*)A)[i] = v;
  }
}

// ---------------- fused layer kernel ----------------
// One output row per wave (proven ~126us shape, R2/R3). hin pre-scaled by nsrc.
//   gather: 4 edge slots x 16 feat-quads, 4 float4 loads in flight per lane
//   GEMM:   readlane-broadcast, W staged in LDS (NO register-hoisted W -> no
//           spills; VGPR ~48 -> 8 waves/SIMD)
//   hout[r] = scale_out ? relu(.)*nsrc[r] : relu(.)
__global__ void __launch_bounds__(256) k_layer(
    const float* __restrict__ hin, const float* __restrict__ ndst,
    const float* __restrict__ nsrc, const int* __restrict__ row_off,
    const int* __restrict__ csr_src, const float* __restrict__ W,
    const float* __restrict__ b, float* __restrict__ hout, int n, int scale_out) {
  __shared__ float Wsh[DFEAT * DFEAT];
  for (int idx = threadIdx.x; idx < DFEAT * DFEAT; idx += blockDim.x) Wsh[idx] = W[idx];
  __syncthreads();

  const int lane = threadIdx.x & 63;
  const int f4 = (lane & 15) * 4;  // feature offset of this lane's quad
  const int e = lane >> 4;         // edge slot 0..3
  const float bias = b[lane];

  int wid = blockIdx.x * (blockDim.x >> 6) + (threadIdx.x >> 6);
  int nw = gridDim.x * (blockDim.x >> 6);

  for (int r = wid; r < n; r += nw) {
    int beg = row_off[r], end = row_off[r + 1];
    float sx0 = 0, sy0 = 0, sz0 = 0, sw0 = 0;
    float sx1 = 0, sy1 = 0, sz1 = 0, sw1 = 0;
    float sx2 = 0, sy2 = 0, sz2 = 0, sw2 = 0;
    float sx3 = 0, sy3 = 0, sz3 = 0, sw3 = 0;
    int k = beg + e;
    // 4 gathers in flight per lane: one iteration covers a deg-16 row
    for (; k + 12 < end; k += 16) {
      int sA = csr_src[k];
      int sB = csr_src[k + 4];
      int sC = csr_src[k + 8];
      int sD = csr_src[k + 12];
      const float4 vA = *(const float4*)(hin + sA * DFEAT + f4);
      const float4 vB = *(const float4*)(hin + sB * DFEAT + f4);
      const float4 vC = *(const float4*)(hin + sC * DFEAT + f4);
      const float4 vD = *(const float4*)(hin + sD * DFEAT + f4);
      sx0 += vA.x; sy0 += vA.y; sz0 += vA.z; sw0 += vA.w;
      sx1 += vB.x; sy1 += vB.y; sz1 += vB.z; sw1 += vB.w;
      sx2 += vC.x; sy2 += vC.y; sz2 += vC.z; sw2 += vC.w;
      sx3 += vD.x; sy3 += vD.y; sz3 += vD.z; sw3 += vD.w;
    }
    for (; k < end; k += 4) {
      int sA = csr_src[k];
      const float4 vA = *(const float4*)(hin + sA * DFEAT + f4);
      sx0 += vA.x; sy0 += vA.y; sz0 += vA.z; sw0 += vA.w;
    }
    float sx = (sx0 + sx1) + (sx2 + sx3);
    float sy = (sy0 + sy1) + (sy2 + sy3);
    float sz = (sz0 + sz1) + (sz2 + sz3);
    float sw = (sw0 + sw1) + (sw2 + sw3);
    // reduce across the 4 edge slots (all lanes end with quad (lane&15) sum)
    sx += __shfl_xor(sx, 16); sy += __shfl_xor(sy, 16);
    sz += __shfl_xor(sz, 16); sw += __shfl_xor(sw, 16);
    sx += __shfl_xor(sx, 32); sy += __shfl_xor(sy, 32);
    sz += __shfl_xor(sz, 32); sw += __shfl_xor(sw, 32);

    float nd = ndst[r];
    sx *= nd; sy *= nd; sz *= nd; sw *= nd;

    // GEMM: out[lane] = sum_k a[k] * W[k][lane]; broadcast via constant-lane shfl.
    // 4 independent accumulator chains; W from LDS (2-way bank alias = free).
    float a0 = bias, a1 = 0.0f, a2 = 0.0f, a3 = 0.0f;
#pragma unroll
    for (int q = 0; q < 16; q += 4) {
      a0 = fmaf(__shfl(sx, q),     Wsh[(4 * q + 0) * DFEAT + lane],  a0);
      a0 = fmaf(__shfl(sy, q),     Wsh[(4 * q + 1) * DFEAT + lane],  a0);
      a0 = fmaf(__shfl(sz, q),     Wsh[(4 * q + 2) * DFEAT + lane],  a0);
      a0 = fmaf(__shfl(sw, q),     Wsh[(4 * q + 3) * DFEAT + lane],  a0);
      a1 = fmaf(__shfl(sx, q + 1), Wsh[(4 * q + 4) * DFEAT + lane],  a1);
      a1 = fmaf(__shfl(sy, q + 1), Wsh[(4 * q + 5) * DFEAT + lane],  a1);
      a1 = fmaf(__shfl(sz, q + 1), Wsh[(4 * q + 6) * DFEAT + lane],  a1);
      a1 = fmaf(__shfl(sw, q + 1), Wsh[(4 * q + 7) * DFEAT + lane],  a1);
      a2 = fmaf(__shfl(sx, q + 2), Wsh[(4 * q + 8) * DFEAT + lane],  a2);
      a2 = fmaf(__shfl(sy, q + 2), Wsh[(4 * q + 9) * DFEAT + lane],  a2);
      a2 = fmaf(__shfl(sz, q + 2), Wsh[(4 * q + 10) * DFEAT + lane], a2);
      a2 = fmaf(__shfl(sw, q + 2), Wsh[(4 * q + 11) * DFEAT + lane], a2);
      a3 = fmaf(__shfl(sx, q + 3), Wsh[(4 * q + 12) * DFEAT + lane], a3);
      a3 = fmaf(__shfl(sy, q + 3), Wsh[(4 * q + 13) * DFEAT + lane], a3);
      a3 = fmaf(__shfl(sz, q + 3), Wsh[(4 * q + 14) * DFEAT + lane], a3);
      a3 = fmaf(__shfl(sw, q + 3), Wsh[(4 * q + 15) * DFEAT + lane], a3);
    }
    float acc = (a0 + a1) + (a2 + a3);
    acc = fmaxf(acc, 0.0f);
    if (scale_out) acc *= nsrc[r];
    hout[r * DFEAT + lane] = acc;
  }
}

// ---------------- launch ----------------

extern "C" void kernel_launch(void* const* d_in, const int* in_sizes, int n_in,
                              void* d_out, int out_size, void* d_ws, size_t ws_size,
                              hipStream_t stream) {
  const float* x = (const float*)d_in[0];
  const int* ei = (const int*)d_in[1];
  const float* Ws = (const float*)d_in[2];
  const float* bs = (const float*)d_in[3];
  float* out = (float*)d_out;

  const int N = in_sizes[0] / DFEAT;
  const int E = in_sizes[1] / 2;
  const int L = in_sizes[2] / (DFEAT * DFEAT);
  const int* src = ei;
  const int* dst = ei + E;
  const int NB = (N + BSZ - 1) >> BUCKET_SHIFT;  // 391 for N=100K

  // workspace carve-up (256B-aligned)
  char* w = (char*)d_ws;
  auto alloc = [&](size_t bytes) -> void* {
    void* p = (void*)w;
    w += (bytes + 255) & ~(size_t)255;
    return p;
  };
  int* cnts = (int*)alloc(sizeof(int) * 2 * NB_MAX);       // dst_cnt | src_cnt
  int* dst_cnt = cnts;
  int* src_cnt = cnts + NB_MAX;
  int* dst_base = (int*)alloc(sizeof(int) * (NB_MAX + 1));
  int* src_base = (int*)alloc(sizeof(int) * (NB_MAX + 1));
  int* dst_cur = (int*)alloc(sizeof(int) * NB_MAX);
  int* src_cur = (int*)alloc(sizeof(int) * NB_MAX);
  float* nsrc = (float*)alloc(sizeof(float) * N);
  float* ndst = (float*)alloc(sizeof(float) * N);
  int* row_off = (int*)alloc(sizeof(int) * (N + 1));
  int* csr_src = (int*)alloc(sizeof(int) * E);
  float* A = (float*)alloc(sizeof(float) * N * DFEAT);
  float* B = (float*)alloc(sizeof(float) * N * DFEAT);
  // aliases into B (dead before layer0 writes B):
  unsigned* pairs = (unsigned*)B;                          // 4B * E = 6.4MB
  unsigned char* sloc = (unsigned char*)B + (16u << 20);   // 1B * E at +16MB
  (void)ws_size; (void)n_in; (void)out_size;

  k_zero_i32<<<4, 256, 0, stream>>>(cnts, 2 * NB_MAX);
  k_hist<<<512, 256, 0, stream>>>(src, dst, dst_cnt, src_cnt, E, NB);
  k_scan2<<<1, NB_MAX, 0, stream>>>(dst_cnt, src_cnt, dst_base, src_base,
                                    dst_cur, src_cur, NB, E);
  k_partition<<<PART_BLOCKS, 256, 0, stream>>>(src, dst, dst_cur, src_cur,
                                               pairs, sloc, E, NB);
  k_build_dst<<<NB, BSZ, 0, stream>>>(pairs, dst_base, row_off, ndst, csr_src, N, E);
  k_build_src<<<NB, BSZ, 0, stream>>>(sloc, src_base, nsrc, N);
  k_prescale<<<2048, 256, 0, stream>>>(x, nsrc, A, N * (DFEAT / 4));

  // layer chain: A -> B -> A -> out (gather must not alias its output)
  for (int l = 0; l < L; l++) {
    const float* hin = (l == 0) ? A : ((l & 1) ? B : A);
    float* hout = (l == L - 1) ? out : ((l & 1) ? A : B);
    k_layer<<<2048, 256, 0, stream>>>(hin, ndst, nsrc, row_off, csr_src,
                                      Ws + l * DFEAT * DFEAT, bs + l * DFEAT,
                                      hout, N, l != L - 1);
  }
}

// Round 8
// 586.139 us; speedup vs baseline: 3.8014x; 1.0159x over previous
//
#include <hip/hip_runtime.h>
#include <math.h>

#define DFEAT 64
#define BUCKET_SHIFT 8          // 256 nodes per bucket
#define BSZ (1 << BUCKET_SHIFT)
#define NB_MAX 512              // supports N <= 131072
#define PART_BLOCKS 192

static inline int imin(int a, int b) { return a < b ? a : b; }

// ---------------- preprocessing ----------------

__global__ void k_zero_i32(int* __restrict__ p, int n) {
  int i = blockIdx.x * blockDim.x + threadIdx.x;
  int stride = gridDim.x * blockDim.x;
  for (; i < n; i += stride) p[i] = 0;
}

// bucket histograms for dst and src (LDS-only per-edge atomics)
__global__ void __launch_bounds__(256) k_hist(
    const int* __restrict__ src, const int* __restrict__ dst,
    int* __restrict__ dst_cnt, int* __restrict__ src_cnt, int E, int NB) {
  __shared__ int hd[NB_MAX], hs[NB_MAX];
  for (int b = threadIdx.x; b < NB; b += blockDim.x) { hd[b] = 0; hs[b] = 0; }
  __syncthreads();
  int i = blockIdx.x * blockDim.x + threadIdx.x;
  int stride = gridDim.x * blockDim.x;
  for (; i < E; i += stride) {
    atomicAdd(&hd[dst[i] >> BUCKET_SHIFT], 1);
    atomicAdd(&hs[src[i] >> BUCKET_SHIFT], 1);
  }
  __syncthreads();
  for (int b = threadIdx.x; b < NB; b += blockDim.x) {
    if (hd[b]) atomicAdd(&dst_cnt[b], hd[b]);
    if (hs[b]) atomicAdd(&src_cnt[b], hs[b]);
  }
}

// exclusive scans of both bucket-count arrays -> base (NB+1) and live cursors
__global__ void k_scan2(const int* __restrict__ dst_cnt, const int* __restrict__ src_cnt,
                        int* __restrict__ dst_base, int* __restrict__ src_base,
                        int* __restrict__ dst_cur, int* __restrict__ src_cur,
                        int NB, int E) {
  __shared__ int sh[NB_MAX];
  int t = threadIdx.x;
  int v = (t < NB) ? dst_cnt[t] : 0;
  sh[t] = v;
  __syncthreads();
  for (int o = 1; o < NB_MAX; o <<= 1) {
    int x = (t >= o) ? sh[t - o] : 0;
    __syncthreads();
    sh[t] += x;
    __syncthreads();
  }
  if (t < NB) { dst_base[t] = sh[t] - v; dst_cur[t] = sh[t] - v; }
  if (t == 0) dst_base[NB] = E;
  __syncthreads();
  int v2 = (t < NB) ? src_cnt[t] : 0;
  sh[t] = v2;
  __syncthreads();
  for (int o = 1; o < NB_MAX; o <<= 1) {
    int x = (t >= o) ? sh[t - o] : 0;
    __syncthreads();
    sh[t] += x;
    __syncthreads();
  }
  if (t < NB) { src_base[t] = sh[t] - v2; src_cur[t] = sh[t] - v2; }
  if (t == 0) src_base[NB] = E;
}

// coarse partition: (dloc<<24|src) pairs grouped by dst bucket + 1B/edge
// src-local stream grouped by src bucket. One reservation atomic per
// (block,bucket) -> contiguous write runs.
__global__ void __launch_bounds__(256) k_partition(
    const int* __restrict__ src, const int* __restrict__ dst,
    int* __restrict__ dst_cur, int* __restrict__ src_cur,
    unsigned* __restrict__ pairs, unsigned char* __restrict__ sloc, int E, int NB) {
  __shared__ int cd[NB_MAX], cs[NB_MAX];
  const int per = (E + gridDim.x - 1) / gridDim.x;
  int e0 = blockIdx.x * per;
  int e1 = e0 + per; if (e1 > E) e1 = E;
  for (int b = threadIdx.x; b < NB; b += blockDim.x) { cd[b] = 0; cs[b] = 0; }
  __syncthreads();
  for (int i = e0 + threadIdx.x; i < e1; i += blockDim.x) {
    atomicAdd(&cd[dst[i] >> BUCKET_SHIFT], 1);
    atomicAdd(&cs[src[i] >> BUCKET_SHIFT], 1);
  }
  __syncthreads();
  for (int b = threadIdx.x; b < NB; b += blockDim.x) {
    int c = cd[b]; cd[b] = c ? atomicAdd(&dst_cur[b], c) : 0;
    int c2 = cs[b]; cs[b] = c2 ? atomicAdd(&src_cur[b], c2) : 0;
  }
  __syncthreads();
  for (int i = e0 + threadIdx.x; i < e1; i += blockDim.x) {
    int d = dst[i], s = src[i];
    int p = atomicAdd(&cd[d >> BUCKET_SHIFT], 1);
    pairs[p] = ((unsigned)(d & (BSZ - 1)) << 24) | (unsigned)s;
    int q = atomicAdd(&cs[s >> BUCKET_SHIFT], 1);
    sloc[q] = (unsigned char)(s & (BSZ - 1));
  }
}

// one block per dst bucket: LDS in-degree count + scan -> row_off, ndst, csr fill
__global__ void __launch_bounds__(256) k_build_dst(
    const unsigned* __restrict__ pairs, const int* __restrict__ dst_base,
    int* __restrict__ row_off, float* __restrict__ ndst, int* __restrict__ csr_src,
    int N, int E) {
  __shared__ int cnt[BSZ];
  __shared__ int pos[BSZ];
  int b = blockIdx.x, t = threadIdx.x;
  int s0 = dst_base[b], s1 = dst_base[b + 1];
  cnt[t] = 0;
  __syncthreads();
  for (int i = s0 + t; i < s1; i += BSZ) atomicAdd(&cnt[pairs[i] >> 24], 1);
  __syncthreads();
  int c = cnt[t];
  pos[t] = c;
  __syncthreads();
  for (int o = 1; o < BSZ; o <<= 1) {
    int x = (t >= o) ? pos[t - o] : 0;
    __syncthreads();
    pos[t] += x;
    __syncthreads();
  }
  int excl = pos[t] - c;
  int node = (b << BUCKET_SHIFT) + t;
  if (node < N) {
    row_off[node] = s0 + excl;
    ndst[node] = c > 0 ? rsqrtf((float)c) : 0.0f;
  }
  __syncthreads();
  pos[t] = excl;  // live cursors
  __syncthreads();
  for (int i = s0 + t; i < s1; i += BSZ) {
    unsigned pr = pairs[i];
    int p = atomicAdd(&pos[pr >> 24], 1);
    csr_src[s0 + p] = (int)(pr & 0xFFFFFFu);
  }
  if (b == 0 && t == 0) row_off[N] = E;
}

// one block per src bucket: LDS out-degree count -> nsrc (dense write)
__global__ void __launch_bounds__(256) k_build_src(
    const unsigned char* __restrict__ sloc, const int* __restrict__ src_base,
    float* __restrict__ nsrc, int N) {
  __shared__ int cnt[BSZ];
  int b = blockIdx.x, t = threadIdx.x;
  int s0 = src_base[b], s1 = src_base[b + 1];
  cnt[t] = 0;
  __syncthreads();
  for (int i = s0 + t; i < s1; i += BSZ) atomicAdd(&cnt[sloc[i]], 1);
  __syncthreads();
  int node = (b << BUCKET_SHIFT) + t;
  if (node < N) nsrc[node] = cnt[t] > 0 ? rsqrtf((float)cnt[t]) : 0.0f;
}

// A[i] = x[i] * nsrc[row]   (float4-vectorized; nq = N*16 quads)
__global__ void __launch_bounds__(256) k_prescale(const float* __restrict__ x,
                                                  const float* __restrict__ nsrc,
                                                  float* __restrict__ A, int nq) {
  int i = blockIdx.x * blockDim.x + threadIdx.x;
  int stride = gridDim.x * blockDim.x;
  for (; i < nq; i += stride) {
    int row = i >> 4;
    float4 v = ((const float4*)x)[i];
    float s = nsrc[row];
    v.x *= s; v.y *= s; v.z *= s; v.w *= s;
    ((float4*)A)[i] = v;
  }
}

// ---------------- aggregation kernel (pure gather) ----------------
// One row per wave; 4 edge slots x 16 feat-quads; 4 float4 loads in flight per
// lane; NOTHING else in the row loop (GEMM split out) -> the compiler can
// pipeline the next row's index/gather loads behind the adds. ~45 VGPR, no LDS
// -> 8 waves/SIMD. Output agg[r] = ndst[r] * sum_{e in row} hin[src_e]
// (hin already pre-scaled by nsrc).
__global__ void __launch_bounds__(256) k_agg(
    const float* __restrict__ hin, const float* __restrict__ ndst,
    const int* __restrict__ row_off, const int* __restrict__ csr_src,
    float* __restrict__ agg, int n) {
  const int lane = threadIdx.x & 63;
  const int f4 = (lane & 15) * 4;  // feature offset of this lane's quad
  const int e = lane >> 4;         // edge slot 0..3

  int wid = blockIdx.x * (blockDim.x >> 6) + (threadIdx.x >> 6);
  int nw = gridDim.x * (blockDim.x >> 6);

  for (int r = wid; r < n; r += nw) {
    int beg = row_off[r], end = row_off[r + 1];
    float sx0 = 0, sy0 = 0, sz0 = 0, sw0 = 0;
    float sx1 = 0, sy1 = 0, sz1 = 0, sw1 = 0;
    float sx2 = 0, sy2 = 0, sz2 = 0, sw2 = 0;
    float sx3 = 0, sy3 = 0, sz3 = 0, sw3 = 0;
    int k = beg + e;
    // 4 gathers in flight per lane: one iteration covers a deg-16 row
    for (; k + 12 < end; k += 16) {
      int sA = csr_src[k];
      int sB = csr_src[k + 4];
      int sC = csr_src[k + 8];
      int sD = csr_src[k + 12];
      const float4 vA = *(const float4*)(hin + sA * DFEAT + f4);
      const float4 vB = *(const float4*)(hin + sB * DFEAT + f4);
      const float4 vC = *(const float4*)(hin + sC * DFEAT + f4);
      const float4 vD = *(const float4*)(hin + sD * DFEAT + f4);
      sx0 += vA.x; sy0 += vA.y; sz0 += vA.z; sw0 += vA.w;
      sx1 += vB.x; sy1 += vB.y; sz1 += vB.z; sw1 += vB.w;
      sx2 += vC.x; sy2 += vC.y; sz2 += vC.z; sw2 += vC.w;
      sx3 += vD.x; sy3 += vD.y; sz3 += vD.z; sw3 += vD.w;
    }
    for (; k < end; k += 4) {
      int sA = csr_src[k];
      const float4 vA = *(const float4*)(hin + sA * DFEAT + f4);
      sx0 += vA.x; sy0 += vA.y; sz0 += vA.z; sw0 += vA.w;
    }
    float sx = (sx0 + sx1) + (sx2 + sx3);
    float sy = (sy0 + sy1) + (sy2 + sy3);
    float sz = (sz0 + sz1) + (sz2 + sz3);
    float sw = (sw0 + sw1) + (sw2 + sw3);
    // reduce across the 4 edge slots
    sx += __shfl_xor(sx, 16); sy += __shfl_xor(sy, 16);
    sz += __shfl_xor(sz, 16); sw += __shfl_xor(sw, 16);
    sx += __shfl_xor(sx, 32); sy += __shfl_xor(sy, 32);
    sz += __shfl_xor(sz, 32); sw += __shfl_xor(sw, 32);

    float nd = ndst[r];
    if (e == 0) {
      float4 v = make_float4(sx * nd, sy * nd, sz * nd, sw * nd);
      *(float4*)(agg + r * DFEAT + f4) = v;
    }
  }
}

// ---------------- dense GEMM + relu kernel ----------------
// out[r][j] = relu( agg[r] @ W + b )[j], optionally * nsrc[r] (fold next
// layer's src-norm). SAFE IN-PLACE (out==agg): each wave reads its own row
// element into `a` before any write; row values travel via shfl, not memory.
__global__ void __launch_bounds__(256) k_gemm(
    const float* __restrict__ agg, const float* __restrict__ nsrc,
    const float* __restrict__ W, const float* __restrict__ b,
    float* __restrict__ out, int n, int scale_out) {
  __shared__ float Wsh[DFEAT * DFEAT];
  for (int idx = threadIdx.x; idx < DFEAT * DFEAT; idx += blockDim.x) Wsh[idx] = W[idx];
  __syncthreads();
  const int lane = threadIdx.x & 63;
  const float bias = b[lane];
  int wid = blockIdx.x * (blockDim.x >> 6) + (threadIdx.x >> 6);
  int nw = gridDim.x * (blockDim.x >> 6);
  for (int r = wid; r < n; r += nw) {
    float a = agg[r * DFEAT + lane];
    float a0 = bias, a1 = 0.0f, a2 = 0.0f, a3 = 0.0f;
#pragma unroll
    for (int q = 0; q < 64; q += 4) {
      a0 = fmaf(__shfl(a, q),     Wsh[(q + 0) * DFEAT + lane], a0);
      a1 = fmaf(__shfl(a, q + 1), Wsh[(q + 1) * DFEAT + lane], a1);
      a2 = fmaf(__shfl(a, q + 2), Wsh[(q + 2) * DFEAT + lane], a2);
      a3 = fmaf(__shfl(a, q + 3), Wsh[(q + 3) * DFEAT + lane], a3);
    }
    float acc = (a0 + a1) + (a2 + a3);
    acc = fmaxf(acc, 0.0f);
    if (scale_out) acc *= nsrc[r];
    out[r * DFEAT + lane] = acc;
  }
}

// ---------------- launch ----------------

extern "C" void kernel_launch(void* const* d_in, const int* in_sizes, int n_in,
                              void* d_out, int out_size, void* d_ws, size_t ws_size,
                              hipStream_t stream) {
  const float* x = (const float*)d_in[0];
  const int* ei = (const int*)d_in[1];
  const float* Ws = (const float*)d_in[2];
  const float* bs = (const float*)d_in[3];
  float* out = (float*)d_out;

  const int N = in_sizes[0] / DFEAT;
  const int E = in_sizes[1] / 2;
  const int L = in_sizes[2] / (DFEAT * DFEAT);
  const int* src = ei;
  const int* dst = ei + E;
  const int NB = (N + BSZ - 1) >> BUCKET_SHIFT;  // 391 for N=100K

  // workspace carve-up (256B-aligned)
  char* w = (char*)d_ws;
  auto alloc = [&](size_t bytes) -> void* {
    void* p = (void*)w;
    w += (bytes + 255) & ~(size_t)255;
    return p;
  };
  int* cnts = (int*)alloc(sizeof(int) * 2 * NB_MAX);       // dst_cnt | src_cnt
  int* dst_cnt = cnts;
  int* src_cnt = cnts + NB_MAX;
  int* dst_base = (int*)alloc(sizeof(int) * (NB_MAX + 1));
  int* src_base = (int*)alloc(sizeof(int) * (NB_MAX + 1));
  int* dst_cur = (int*)alloc(sizeof(int) * NB_MAX);
  int* src_cur = (int*)alloc(sizeof(int) * NB_MAX);
  float* nsrc = (float*)alloc(sizeof(float) * N);
  float* ndst = (float*)alloc(sizeof(float) * N);
  int* row_off = (int*)alloc(sizeof(int) * (N + 1));
  int* csr_src = (int*)alloc(sizeof(int) * E);
  float* A = (float*)alloc(sizeof(float) * N * DFEAT);
  float* B = (float*)alloc(sizeof(float) * N * DFEAT);
  // aliases into B (dead before layer0's k_agg writes B):
  unsigned* pairs = (unsigned*)B;                          // 4B * E = 6.4MB
  unsigned char* sloc = (unsigned char*)B + (16u << 20);   // 1B * E at +16MB
  (void)ws_size; (void)n_in; (void)out_size;

  k_zero_i32<<<4, 256, 0, stream>>>(cnts, 2 * NB_MAX);
  k_hist<<<512, 256, 0, stream>>>(src, dst, dst_cnt, src_cnt, E, NB);
  k_scan2<<<1, NB_MAX, 0, stream>>>(dst_cnt, src_cnt, dst_base, src_base,
                                    dst_cur, src_cur, NB, E);
  k_partition<<<PART_BLOCKS, 256, 0, stream>>>(src, dst, dst_cur, src_cur,
                                               pairs, sloc, E, NB);
  k_build_dst<<<NB, BSZ, 0, stream>>>(pairs, dst_base, row_off, ndst, csr_src, N, E);
  k_build_src<<<NB, BSZ, 0, stream>>>(sloc, src_base, nsrc, N);
  k_prescale<<<2048, 256, 0, stream>>>(x, nsrc, A, N * (DFEAT / 4));

  // layer l: agg hin -> G (other buffer), gemm G -> G in place (or -> out last)
  // chain: A -agg-> B -gemm-> B ; B -agg-> A -gemm-> A ; A -agg-> B -gemm-> out
  for (int l = 0; l < L; l++) {
    const float* hin = (l & 1) ? B : A;
    float* G = (l & 1) ? A : B;
    float* ho = (l == L - 1) ? out : G;
    k_agg<<<2048, 256, 0, stream>>>(hin, ndst, row_off, csr_src, G, N);
    k_gemm<<<2048, 256, 0, stream>>>(G, nsrc, Ws + l * DFEAT * DFEAT,
                                     bs + l * DFEAT, ho, N, l != L - 1);
  }
}

// Round 10
// 565.020 us; speedup vs baseline: 3.9435x; 1.0374x over previous
//
#include <hip/hip_runtime.h>
#include <math.h>

#define DFEAT 64
#define BUCKET_SHIFT 8          // 256 nodes per bucket
#define BSZ (1 << BUCKET_SHIFT)
#define NB_MAX 512              // supports N <= 131072
#define PART_BLOCKS 192

static inline int imin(int a, int b) { return a < b ? a : b; }

// ---------------- preprocessing ----------------

__global__ void k_zero_i32(int* __restrict__ p, int n) {
  int i = blockIdx.x * blockDim.x + threadIdx.x;
  int stride = gridDim.x * blockDim.x;
  for (; i < n; i += stride) p[i] = 0;
}

// bucket histograms for dst and src (LDS-only per-edge atomics)
__global__ void __launch_bounds__(256) k_hist(
    const int* __restrict__ src, const int* __restrict__ dst,
    int* __restrict__ dst_cnt, int* __restrict__ src_cnt, int E, int NB) {
  __shared__ int hd[NB_MAX], hs[NB_MAX];
  for (int b = threadIdx.x; b < NB; b += blockDim.x) { hd[b] = 0; hs[b] = 0; }
  __syncthreads();
  int i = blockIdx.x * blockDim.x + threadIdx.x;
  int stride = gridDim.x * blockDim.x;
  for (; i < E; i += stride) {
    atomicAdd(&hd[dst[i] >> BUCKET_SHIFT], 1);
    atomicAdd(&hs[src[i] >> BUCKET_SHIFT], 1);
  }
  __syncthreads();
  for (int b = threadIdx.x; b < NB; b += blockDim.x) {
    if (hd[b]) atomicAdd(&dst_cnt[b], hd[b]);
    if (hs[b]) atomicAdd(&src_cnt[b], hs[b]);
  }
}

// exclusive scans of both bucket-count arrays -> base (NB+1) and live cursors
__global__ void k_scan2(const int* __restrict__ dst_cnt, const int* __restrict__ src_cnt,
                        int* __restrict__ dst_base, int* __restrict__ src_base,
                        int* __restrict__ dst_cur, int* __restrict__ src_cur,
                        int NB, int E) {
  __shared__ int sh[NB_MAX];
  int t = threadIdx.x;
  int v = (t < NB) ? dst_cnt[t] : 0;
  sh[t] = v;
  __syncthreads();
  for (int o = 1; o < NB_MAX; o <<= 1) {
    int x = (t >= o) ? sh[t - o] : 0;
    __syncthreads();
    sh[t] += x;
    __syncthreads();
  }
  if (t < NB) { dst_base[t] = sh[t] - v; dst_cur[t] = sh[t] - v; }
  if (t == 0) dst_base[NB] = E;
  __syncthreads();
  int v2 = (t < NB) ? src_cnt[t] : 0;
  sh[t] = v2;
  __syncthreads();
  for (int o = 1; o < NB_MAX; o <<= 1) {
    int x = (t >= o) ? sh[t - o] : 0;
    __syncthreads();
    sh[t] += x;
    __syncthreads();
  }
  if (t < NB) { src_base[t] = sh[t] - v2; src_cur[t] = sh[t] - v2; }
  if (t == 0) src_base[NB] = E;
}

// coarse partition: (dloc<<24|src) pairs grouped by dst bucket + 1B/edge
// src-local stream grouped by src bucket. One reservation atomic per
// (block,bucket) -> contiguous write runs.
__global__ void __launch_bounds__(256) k_partition(
    const int* __restrict__ src, const int* __restrict__ dst,
    int* __restrict__ dst_cur, int* __restrict__ src_cur,
    unsigned* __restrict__ pairs, unsigned char* __restrict__ sloc, int E, int NB) {
  __shared__ int cd[NB_MAX], cs[NB_MAX];
  const int per = (E + gridDim.x - 1) / gridDim.x;
  int e0 = blockIdx.x * per;
  int e1 = e0 + per; if (e1 > E) e1 = E;
  for (int b = threadIdx.x; b < NB; b += blockDim.x) { cd[b] = 0; cs[b] = 0; }
  __syncthreads();
  for (int i = e0 + threadIdx.x; i < e1; i += blockDim.x) {
    atomicAdd(&cd[dst[i] >> BUCKET_SHIFT], 1);
    atomicAdd(&cs[src[i] >> BUCKET_SHIFT], 1);
  }
  __syncthreads();
  for (int b = threadIdx.x; b < NB; b += blockDim.x) {
    int c = cd[b]; cd[b] = c ? atomicAdd(&dst_cur[b], c) : 0;
    int c2 = cs[b]; cs[b] = c2 ? atomicAdd(&src_cur[b], c2) : 0;
  }
  __syncthreads();
  for (int i = e0 + threadIdx.x; i < e1; i += blockDim.x) {
    int d = dst[i], s = src[i];
    int p = atomicAdd(&cd[d >> BUCKET_SHIFT], 1);
    pairs[p] = ((unsigned)(d & (BSZ - 1)) << 24) | (unsigned)s;
    int q = atomicAdd(&cs[s >> BUCKET_SHIFT], 1);
    sloc[q] = (unsigned char)(s & (BSZ - 1));
  }
}

// one block per dst bucket: LDS in-degree count + scan -> row_off, ndst, csr fill
__global__ void __launch_bounds__(256) k_build_dst(
    const unsigned* __restrict__ pairs, const int* __restrict__ dst_base,
    int* __restrict__ row_off, float* __restrict__ ndst, int* __restrict__ csr_src,
    int N, int E) {
  __shared__ int cnt[BSZ];
  __shared__ int pos[BSZ];
  int b = blockIdx.x, t = threadIdx.x;
  int s0 = dst_base[b], s1 = dst_base[b + 1];
  cnt[t] = 0;
  __syncthreads();
  for (int i = s0 + t; i < s1; i += BSZ) atomicAdd(&cnt[pairs[i] >> 24], 1);
  __syncthreads();
  int c = cnt[t];
  pos[t] = c;
  __syncthreads();
  for (int o = 1; o < BSZ; o <<= 1) {
    int x = (t >= o) ? pos[t - o] : 0;
    __syncthreads();
    pos[t] += x;
    __syncthreads();
  }
  int excl = pos[t] - c;
  int node = (b << BUCKET_SHIFT) + t;
  if (node < N) {
    row_off[node] = s0 + excl;
    ndst[node] = c > 0 ? rsqrtf((float)c) : 0.0f;
  }
  __syncthreads();
  pos[t] = excl;  // live cursors
  __syncthreads();
  for (int i = s0 + t; i < s1; i += BSZ) {
    unsigned pr = pairs[i];
    int p = atomicAdd(&pos[pr >> 24], 1);
    csr_src[s0 + p] = (int)(pr & 0xFFFFFFu);
  }
  if (b == 0 && t == 0) row_off[N] = E;
}

// one block per src bucket: LDS out-degree count -> nsrc (dense write)
__global__ void __launch_bounds__(256) k_build_src(
    const unsigned char* __restrict__ sloc, const int* __restrict__ src_base,
    float* __restrict__ nsrc, int N) {
  __shared__ int cnt[BSZ];
  int b = blockIdx.x, t = threadIdx.x;
  int s0 = src_base[b], s1 = src_base[b + 1];
  cnt[t] = 0;
  __syncthreads();
  for (int i = s0 + t; i < s1; i += BSZ) atomicAdd(&cnt[sloc[i]], 1);
  __syncthreads();
  int node = (b << BUCKET_SHIFT) + t;
  if (node < N) nsrc[node] = cnt[t] > 0 ? rsqrtf((float)cnt[t]) : 0.0f;
}

// A[i] = x[i] * nsrc[row]   (float4-vectorized; nq = N*16 quads)
__global__ void __launch_bounds__(256) k_prescale(const float* __restrict__ x,
                                                  const float* __restrict__ nsrc,
                                                  float* __restrict__ A, int nq) {
  int i = blockIdx.x * blockDim.x + threadIdx.x;
  int stride = gridDim.x * blockDim.x;
  for (; i < nq; i += stride) {
    int row = i >> 4;
    float4 v = ((const float4*)x)[i];
    float s = nsrc[row];
    v.x *= s; v.y *= s; v.z *= s; v.w *= s;
    ((float4*)A)[i] = v;
  }
}

// ---------------- aggregation kernel (pure gather) ----------------
// One row per wave; 4 edge slots x 16 feat-quads; 4 float4 loads in flight per
// lane; NOTHING else in the row loop. ~45 VGPR, no LDS -> 8 waves/SIMD.
// Output agg[r] = ndst[r] * sum_{e in row} hin[src_e] (hin pre-scaled by nsrc).
__global__ void __launch_bounds__(256) k_agg(
    const float* __restrict__ hin, const float* __restrict__ ndst,
    const int* __restrict__ row_off, const int* __restrict__ csr_src,
    float* __restrict__ agg, int n) {
  const int lane = threadIdx.x & 63;
  const int f4 = (lane & 15) * 4;  // feature offset of this lane's quad
  const int e = lane >> 4;         // edge slot 0..3

  int wid = blockIdx.x * (blockDim.x >> 6) + (threadIdx.x >> 6);
  int nw = gridDim.x * (blockDim.x >> 6);

  for (int r = wid; r < n; r += nw) {
    int beg = row_off[r], end = row_off[r + 1];
    float sx0 = 0, sy0 = 0, sz0 = 0, sw0 = 0;
    float sx1 = 0, sy1 = 0, sz1 = 0, sw1 = 0;
    float sx2 = 0, sy2 = 0, sz2 = 0, sw2 = 0;
    float sx3 = 0, sy3 = 0, sz3 = 0, sw3 = 0;
    int k = beg + e;
    // 4 gathers in flight per lane: one iteration covers a deg-16 row
    for (; k + 12 < end; k += 16) {
      int sA = csr_src[k];
      int sB = csr_src[k + 4];
      int sC = csr_src[k + 8];
      int sD = csr_src[k + 12];
      const float4 vA = *(const float4*)(hin + sA * DFEAT + f4);
      const float4 vB = *(const float4*)(hin + sB * DFEAT + f4);
      const float4 vC = *(const float4*)(hin + sC * DFEAT + f4);
      const float4 vD = *(const float4*)(hin + sD * DFEAT + f4);
      sx0 += vA.x; sy0 += vA.y; sz0 += vA.z; sw0 += vA.w;
      sx1 += vB.x; sy1 += vB.y; sz1 += vB.z; sw1 += vB.w;
      sx2 += vC.x; sy2 += vC.y; sz2 += vC.z; sw2 += vC.w;
      sx3 += vD.x; sy3 += vD.y; sz3 += vD.z; sw3 += vD.w;
    }
    for (; k < end; k += 4) {
      int sA = csr_src[k];
      const float4 vA = *(const float4*)(hin + sA * DFEAT + f4);
      sx0 += vA.x; sy0 += vA.y; sz0 += vA.z; sw0 += vA.w;
    }
    float sx = (sx0 + sx1) + (sx2 + sx3);
    float sy = (sy0 + sy1) + (sy2 + sy3);
    float sz = (sz0 + sz1) + (sz2 + sz3);
    float sw = (sw0 + sw1) + (sw2 + sw3);
    // reduce across the 4 edge slots
    sx += __shfl_xor(sx, 16); sy += __shfl_xor(sy, 16);
    sz += __shfl_xor(sz, 16); sw += __shfl_xor(sw, 16);
    sx += __shfl_xor(sx, 32); sy += __shfl_xor(sy, 32);
    sz += __shfl_xor(sz, 32); sw += __shfl_xor(sw, 32);

    float nd = ndst[r];
    if (e == 0) {
      float4 v = make_float4(sx * nd, sy * nd, sz * nd, sw * nd);
      *(float4*)(agg + r * DFEAT + f4) = v;
    }
  }
}

// ---------------- dense GEMM + relu kernel ----------------
// out[r][j] = relu( agg[r] @ W + b )[j], optionally * nsrc[r].
// W column register-hoisted: wreg[k] = W[k][lane] (all indices literal after
// unroll -> stays in VGPRs, ~85 total, no LDS, no per-row memory ops in the
// GEMM). Inner loop = 64 readlane broadcasts + 64 FMAs per row.
// SAFE IN-PLACE (out==agg): wave reads its own row element before any write.
__global__ void __launch_bounds__(256) k_gemm(
    const float* __restrict__ agg, const float* __restrict__ nsrc,
    const float* __restrict__ W, const float* __restrict__ b,
    float* __restrict__ out, int n, int scale_out) {
  const int lane = threadIdx.x & 63;
  float wreg[DFEAT];
#pragma unroll
  for (int k = 0; k < DFEAT; k++) wreg[k] = W[k * DFEAT + lane];
  const float bias = b[lane];
  int wid = blockIdx.x * (blockDim.x >> 6) + (threadIdx.x >> 6);
  int nw = gridDim.x * (blockDim.x >> 6);
  for (int r = wid; r < n; r += nw) {
    float a = agg[r * DFEAT + lane];
    float a0 = bias, a1 = 0.0f, a2 = 0.0f, a3 = 0.0f;
#pragma unroll
    for (int q = 0; q < 64; q += 4) {
      a0 = fmaf(__shfl(a, q),     wreg[q + 0], a0);
      a1 = fmaf(__shfl(a, q + 1), wreg[q + 1], a1);
      a2 = fmaf(__shfl(a, q + 2), wreg[q + 2], a2);
      a3 = fmaf(__shfl(a, q + 3), wreg[q + 3], a3);
    }
    float acc = (a0 + a1) + (a2 + a3);
    acc = fmaxf(acc, 0.0f);
    if (scale_out) acc *= nsrc[r];
    out[r * DFEAT + lane] = acc;
  }
}

// ---------------- launch ----------------

extern "C" void kernel_launch(void* const* d_in, const int* in_sizes, int n_in,
                              void* d_out, int out_size, void* d_ws, size_t ws_size,
                              hipStream_t stream) {
  const float* x = (const float*)d_in[0];
  const int* ei = (const int*)d_in[1];
  const float* Ws = (const float*)d_in[2];
  const float* bs = (const float*)d_in[3];
  float* out = (float*)d_out;

  const int N = in_sizes[0] / DFEAT;
  const int E = in_sizes[1] / 2;
  const int L = in_sizes[2] / (DFEAT * DFEAT);
  const int* src = ei;
  const int* dst = ei + E;
  const int NB = (N + BSZ - 1) >> BUCKET_SHIFT;  // 391 for N=100K

  // workspace carve-up (256B-aligned)
  char* w = (char*)d_ws;
  auto alloc = [&](size_t bytes) -> void* {
    void* p = (void*)w;
    w += (bytes + 255) & ~(size_t)255;
    return p;
  };
  int* cnts = (int*)alloc(sizeof(int) * 2 * NB_MAX);       // dst_cnt | src_cnt
  int* dst_cnt = cnts;
  int* src_cnt = cnts + NB_MAX;
  int* dst_base = (int*)alloc(sizeof(int) * (NB_MAX + 1));
  int* src_base = (int*)alloc(sizeof(int) * (NB_MAX + 1));
  int* dst_cur = (int*)alloc(sizeof(int) * NB_MAX);
  int* src_cur = (int*)alloc(sizeof(int) * NB_MAX);
  float* nsrc = (float*)alloc(sizeof(float) * N);
  float* ndst = (float*)alloc(sizeof(float) * N);
  int* row_off = (int*)alloc(sizeof(int) * (N + 1));
  int* csr_src = (int*)alloc(sizeof(int) * E);
  float* A = (float*)alloc(sizeof(float) * N * DFEAT);
  float* B = (float*)alloc(sizeof(float) * N * DFEAT);
  // aliases into B (dead before layer0's k_agg writes B):
  unsigned* pairs = (unsigned*)B;                          // 4B * E = 6.4MB
  unsigned char* sloc = (unsigned char*)B + (16u << 20);   // 1B * E at +16MB
  (void)ws_size; (void)n_in; (void)out_size;

  k_zero_i32<<<4, 256, 0, stream>>>(cnts, 2 * NB_MAX);
  k_hist<<<512, 256, 0, stream>>>(src, dst, dst_cnt, src_cnt, E, NB);
  k_scan2<<<1, NB_MAX, 0, stream>>>(dst_cnt, src_cnt, dst_base, src_base,
                                    dst_cur, src_cur, NB, E);
  k_partition<<<PART_BLOCKS, 256, 0, stream>>>(src, dst, dst_cur, src_cur,
                                               pairs, sloc, E, NB);
  k_build_dst<<<NB, BSZ, 0, stream>>>(pairs, dst_base, row_off, ndst, csr_src, N, E);
  k_build_src<<<NB, BSZ, 0, stream>>>(sloc, src_base, nsrc, N);
  k_prescale<<<2048, 256, 0, stream>>>(x, nsrc, A, N * (DFEAT / 4));

  // layer l: agg hin -> G (other buffer), gemm G -> G in place (or -> out last)
  // chain: A -agg-> B -gemm-> B ; B -agg-> A -gemm-> A ; A -agg-> B -gemm-> out
  for (int l = 0; l < L; l++) {
    const float* hin = (l & 1) ? B : A;
    float* G = (l & 1) ? A : B;
    float* ho = (l == L - 1) ? out : G;
    k_agg<<<2048, 256, 0, stream>>>(hin, ndst, row_off, csr_src, G, N);
    k_gemm<<<2048, 256, 0, stream>>>(G, nsrc, Ws + l * DFEAT * DFEAT,
                                     bs + l * DFEAT, ho, N, l != L - 1);
  }
}

// Round 11
// 448.649 us; speedup vs baseline: 4.9664x; 1.2594x over previous
//
#include <hip/hip_runtime.h>
#include <math.h>

#define DFEAT 64
#define BUCKET_SHIFT 8          // 256 nodes per bucket
#define BSZ (1 << BUCKET_SHIFT)
#define NB_MAX 512              // supports N <= 131072
#define PART_BLOCKS 192

static inline int imin(int a, int b) { return a < b ? a : b; }

// ---------------- preprocessing ----------------

__global__ void k_zero_i32(int* __restrict__ p, int n) {
  int i = blockIdx.x * blockDim.x + threadIdx.x;
  int stride = gridDim.x * blockDim.x;
  for (; i < n; i += stride) p[i] = 0;
}

// bucket histograms for dst and src (LDS-only per-edge atomics)
__global__ void __launch_bounds__(256) k_hist(
    const int* __restrict__ src, const int* __restrict__ dst,
    int* __restrict__ dst_cnt, int* __restrict__ src_cnt, int E, int NB) {
  __shared__ int hd[NB_MAX], hs[NB_MAX];
  for (int b = threadIdx.x; b < NB; b += blockDim.x) { hd[b] = 0; hs[b] = 0; }
  __syncthreads();
  int i = blockIdx.x * blockDim.x + threadIdx.x;
  int stride = gridDim.x * blockDim.x;
  for (; i < E; i += stride) {
    atomicAdd(&hd[dst[i] >> BUCKET_SHIFT], 1);
    atomicAdd(&hs[src[i] >> BUCKET_SHIFT], 1);
  }
  __syncthreads();
  for (int b = threadIdx.x; b < NB; b += blockDim.x) {
    if (hd[b]) atomicAdd(&dst_cnt[b], hd[b]);
    if (hs[b]) atomicAdd(&src_cnt[b], hs[b]);
  }
}

// exclusive scans of both bucket-count arrays -> base (NB+1) and live cursors
__global__ void k_scan2(const int* __restrict__ dst_cnt, const int* __restrict__ src_cnt,
                        int* __restrict__ dst_base, int* __restrict__ src_base,
                        int* __restrict__ dst_cur, int* __restrict__ src_cur,
                        int NB, int E) {
  __shared__ int sh[NB_MAX];
  int t = threadIdx.x;
  int v = (t < NB) ? dst_cnt[t] : 0;
  sh[t] = v;
  __syncthreads();
  for (int o = 1; o < NB_MAX; o <<= 1) {
    int x = (t >= o) ? sh[t - o] : 0;
    __syncthreads();
    sh[t] += x;
    __syncthreads();
  }
  if (t < NB) { dst_base[t] = sh[t] - v; dst_cur[t] = sh[t] - v; }
  if (t == 0) dst_base[NB] = E;
  __syncthreads();
  int v2 = (t < NB) ? src_cnt[t] : 0;
  sh[t] = v2;
  __syncthreads();
  for (int o = 1; o < NB_MAX; o <<= 1) {
    int x = (t >= o) ? sh[t - o] : 0;
    __syncthreads();
    sh[t] += x;
    __syncthreads();
  }
  if (t < NB) { src_base[t] = sh[t] - v2; src_cur[t] = sh[t] - v2; }
  if (t == 0) src_base[NB] = E;
}

// coarse partition: (dloc<<24|src) pairs grouped by dst bucket + 1B/edge
// src-local stream grouped by src bucket. One reservation atomic per
// (block,bucket) -> contiguous write runs.
__global__ void __launch_bounds__(256) k_partition(
    const int* __restrict__ src, const int* __restrict__ dst,
    int* __restrict__ dst_cur, int* __restrict__ src_cur,
    unsigned* __restrict__ pairs, unsigned char* __restrict__ sloc, int E, int NB) {
  __shared__ int cd[NB_MAX], cs[NB_MAX];
  const int per = (E + gridDim.x - 1) / gridDim.x;
  int e0 = blockIdx.x * per;
  int e1 = e0 + per; if (e1 > E) e1 = E;
  for (int b = threadIdx.x; b < NB; b += blockDim.x) { cd[b] = 0; cs[b] = 0; }
  __syncthreads();
  for (int i = e0 + threadIdx.x; i < e1; i += blockDim.x) {
    atomicAdd(&cd[dst[i] >> BUCKET_SHIFT], 1);
    atomicAdd(&cs[src[i] >> BUCKET_SHIFT], 1);
  }
  __syncthreads();
  for (int b = threadIdx.x; b < NB; b += blockDim.x) {
    int c = cd[b]; cd[b] = c ? atomicAdd(&dst_cur[b], c) : 0;
    int c2 = cs[b]; cs[b] = c2 ? atomicAdd(&src_cur[b], c2) : 0;
  }
  __syncthreads();
  for (int i = e0 + threadIdx.x; i < e1; i += blockDim.x) {
    int d = dst[i], s = src[i];
    int p = atomicAdd(&cd[d >> BUCKET_SHIFT], 1);
    pairs[p] = ((unsigned)(d & (BSZ - 1)) << 24) | (unsigned)s;
    int q = atomicAdd(&cs[s >> BUCKET_SHIFT], 1);
    sloc[q] = (unsigned char)(s & (BSZ - 1));
  }
}

// one block per dst bucket: LDS in-degree count + scan -> row_off, ndst, csr fill
__global__ void __launch_bounds__(256) k_build_dst(
    const unsigned* __restrict__ pairs, const int* __restrict__ dst_base,
    int* __restrict__ row_off, float* __restrict__ ndst, int* __restrict__ csr_src,
    int N, int E) {
  __shared__ int cnt[BSZ];
  __shared__ int pos[BSZ];
  int b = blockIdx.x, t = threadIdx.x;
  int s0 = dst_base[b], s1 = dst_base[b + 1];
  cnt[t] = 0;
  __syncthreads();
  for (int i = s0 + t; i < s1; i += BSZ) atomicAdd(&cnt[pairs[i] >> 24], 1);
  __syncthreads();
  int c = cnt[t];
  pos[t] = c;
  __syncthreads();
  for (int o = 1; o < BSZ; o <<= 1) {
    int x = (t >= o) ? pos[t - o] : 0;
    __syncthreads();
    pos[t] += x;
    __syncthreads();
  }
  int excl = pos[t] - c;
  int node = (b << BUCKET_SHIFT) + t;
  if (node < N) {
    row_off[node] = s0 + excl;
    ndst[node] = c > 0 ? rsqrtf((float)c) : 0.0f;
  }
  __syncthreads();
  pos[t] = excl;  // live cursors
  __syncthreads();
  for (int i = s0 + t; i < s1; i += BSZ) {
    unsigned pr = pairs[i];
    int p = atomicAdd(&pos[pr >> 24], 1);
    csr_src[s0 + p] = (int)(pr & 0xFFFFFFu);
  }
  if (b == 0 && t == 0) row_off[N] = E;
}

// one block per src bucket: LDS out-degree count -> nsrc (dense write)
__global__ void __launch_bounds__(256) k_build_src(
    const unsigned char* __restrict__ sloc, const int* __restrict__ src_base,
    float* __restrict__ nsrc, int N) {
  __shared__ int cnt[BSZ];
  int b = blockIdx.x, t = threadIdx.x;
  int s0 = src_base[b], s1 = src_base[b + 1];
  cnt[t] = 0;
  __syncthreads();
  for (int i = s0 + t; i < s1; i += BSZ) atomicAdd(&cnt[sloc[i]], 1);
  __syncthreads();
  int node = (b << BUCKET_SHIFT) + t;
  if (node < N) nsrc[node] = cnt[t] > 0 ? rsqrtf((float)cnt[t]) : 0.0f;
}

// A[i] = x[i] * nsrc[row]   (float4-vectorized; nq = N*16 quads)
__global__ void __launch_bounds__(256) k_prescale(const float* __restrict__ x,
                                                  const float* __restrict__ nsrc,
                                                  float* __restrict__ A, int nq) {
  int i = blockIdx.x * blockDim.x + threadIdx.x;
  int stride = gridDim.x * blockDim.x;
  for (; i < nq; i += stride) {
    int row = i >> 4;
    float4 v = ((const float4*)x)[i];
    float s = nsrc[row];
    v.x *= s; v.y *= s; v.z *= s; v.w *= s;
    ((float4*)A)[i] = v;
  }
}

// ---------------- aggregation kernel (pure gather) ----------------
// One row per wave; 4 edge slots x 16 feat-quads; 4 float4 loads in flight per
// lane; NOTHING else in the row loop. ~45 VGPR, no LDS -> 8 waves/SIMD.
// Output agg[r] = ndst[r] * sum_{e in row} hin[src_e] (hin pre-scaled by nsrc).
__global__ void __launch_bounds__(256) k_agg(
    const float* __restrict__ hin, const float* __restrict__ ndst,
    const int* __restrict__ row_off, const int* __restrict__ csr_src,
    float* __restrict__ agg, int n) {
  const int lane = threadIdx.x & 63;
  const int f4 = (lane & 15) * 4;  // feature offset of this lane's quad
  const int e = lane >> 4;         // edge slot 0..3

  int wid = blockIdx.x * (blockDim.x >> 6) + (threadIdx.x >> 6);
  int nw = gridDim.x * (blockDim.x >> 6);

  for (int r = wid; r < n; r += nw) {
    int beg = row_off[r], end = row_off[r + 1];
    float sx0 = 0, sy0 = 0, sz0 = 0, sw0 = 0;
    float sx1 = 0, sy1 = 0, sz1 = 0, sw1 = 0;
    float sx2 = 0, sy2 = 0, sz2 = 0, sw2 = 0;
    float sx3 = 0, sy3 = 0, sz3 = 0, sw3 = 0;
    int k = beg + e;
    // 4 gathers in flight per lane: one iteration covers a deg-16 row
    for (; k + 12 < end; k += 16) {
      int sA = csr_src[k];
      int sB = csr_src[k + 4];
      int sC = csr_src[k + 8];
      int sD = csr_src[k + 12];
      const float4 vA = *(const float4*)(hin + sA * DFEAT + f4);
      const float4 vB = *(const float4*)(hin + sB * DFEAT + f4);
      const float4 vC = *(const float4*)(hin + sC * DFEAT + f4);
      const float4 vD = *(const float4*)(hin + sD * DFEAT + f4);
      sx0 += vA.x; sy0 += vA.y; sz0 += vA.z; sw0 += vA.w;
      sx1 += vB.x; sy1 += vB.y; sz1 += vB.z; sw1 += vB.w;
      sx2 += vC.x; sy2 += vC.y; sz2 += vC.z; sw2 += vC.w;
      sx3 += vD.x; sy3 += vD.y; sz3 += vD.z; sw3 += vD.w;
    }
    for (; k < end; k += 4) {
      int sA = csr_src[k];
      const float4 vA = *(const float4*)(hin + sA * DFEAT + f4);
      sx0 += vA.x; sy0 += vA.y; sz0 += vA.z; sw0 += vA.w;
    }
    float sx = (sx0 + sx1) + (sx2 + sx3);
    float sy = (sy0 + sy1) + (sy2 + sy3);
    float sz = (sz0 + sz1) + (sz2 + sz3);
    float sw = (sw0 + sw1) + (sw2 + sw3);
    // reduce across the 4 edge slots
    sx += __shfl_xor(sx, 16); sy += __shfl_xor(sy, 16);
    sz += __shfl_xor(sz, 16); sw += __shfl_xor(sw, 16);
    sx += __shfl_xor(sx, 32); sy += __shfl_xor(sy, 32);
    sz += __shfl_xor(sz, 32); sw += __shfl_xor(sw, 32);

    float nd = ndst[r];
    if (e == 0) {
      float4 v = make_float4(sx * nd, sy * nd, sz * nd, sw * nd);
      *(float4*)(agg + r * DFEAT + f4) = v;
    }
  }
}

// ---------------- dense GEMM + relu kernel ----------------
// out[r][j] = relu( agg[r] @ W + b )[j], optionally * nsrc[r].
// W column in VGPRs (wreg[k] = W[k][lane], literal indices). The row values
// a[0..63] are WAVE-UNIFORM scalars: row pointer is readfirstlane-uniform and
// agg/out are distinct __restrict__ buffers (OUT-OF-PLACE), so the compiler
// can emit s_load_dwordx16 for rowp[0..63] -> inner loop is 64x
// v_fmac_f32 v,s,v with ZERO shuffle/LDS ops (the R10 bpermute bottleneck).
__global__ void __launch_bounds__(256) k_gemm(
    const float* __restrict__ agg, const float* __restrict__ nsrc,
    const float* __restrict__ W, const float* __restrict__ b,
    float* __restrict__ out, int n, int scale_out) {
  const int lane = threadIdx.x & 63;
  float wreg[DFEAT];
#pragma unroll
  for (int k = 0; k < DFEAT; k++) wreg[k] = W[k * DFEAT + lane];
  const float bias = b[lane];
  int wid = blockIdx.x * (blockDim.x >> 6) + (threadIdx.x >> 6);
  int nw = gridDim.x * (blockDim.x >> 6);
  for (int r = wid; r < n; r += nw) {
    int ru = __builtin_amdgcn_readfirstlane(r);
    const float* __restrict__ rowp = agg + (size_t)ru * DFEAT;
    float a0 = bias, a1 = 0.0f, a2 = 0.0f, a3 = 0.0f;
#pragma unroll
    for (int q = 0; q < DFEAT; q += 4) {
      a0 = fmaf(rowp[q + 0], wreg[q + 0], a0);
      a1 = fmaf(rowp[q + 1], wreg[q + 1], a1);
      a2 = fmaf(rowp[q + 2], wreg[q + 2], a2);
      a3 = fmaf(rowp[q + 3], wreg[q + 3], a3);
    }
    float acc = (a0 + a1) + (a2 + a3);
    acc = fmaxf(acc, 0.0f);
    if (scale_out) acc *= nsrc[ru];
    out[(size_t)ru * DFEAT + lane] = acc;
  }
}

// ---------------- launch ----------------

extern "C" void kernel_launch(void* const* d_in, const int* in_sizes, int n_in,
                              void* d_out, int out_size, void* d_ws, size_t ws_size,
                              hipStream_t stream) {
  const float* x = (const float*)d_in[0];
  const int* ei = (const int*)d_in[1];
  const float* Ws = (const float*)d_in[2];
  const float* bs = (const float*)d_in[3];
  float* out = (float*)d_out;

  const int N = in_sizes[0] / DFEAT;
  const int E = in_sizes[1] / 2;
  const int L = in_sizes[2] / (DFEAT * DFEAT);
  const int* src = ei;
  const int* dst = ei + E;
  const int NB = (N + BSZ - 1) >> BUCKET_SHIFT;  // 391 for N=100K

  // workspace carve-up (256B-aligned)
  char* w = (char*)d_ws;
  auto alloc = [&](size_t bytes) -> void* {
    void* p = (void*)w;
    w += (bytes + 255) & ~(size_t)255;
    return p;
  };
  int* cnts = (int*)alloc(sizeof(int) * 2 * NB_MAX);       // dst_cnt | src_cnt
  int* dst_cnt = cnts;
  int* src_cnt = cnts + NB_MAX;
  int* dst_base = (int*)alloc(sizeof(int) * (NB_MAX + 1));
  int* src_base = (int*)alloc(sizeof(int) * (NB_MAX + 1));
  int* dst_cur = (int*)alloc(sizeof(int) * NB_MAX);
  int* src_cur = (int*)alloc(sizeof(int) * NB_MAX);
  float* nsrc = (float*)alloc(sizeof(float) * N);
  float* ndst = (float*)alloc(sizeof(float) * N);
  int* row_off = (int*)alloc(sizeof(int) * (N + 1));
  int* csr_src = (int*)alloc(sizeof(int) * E);
  float* A = (float*)alloc(sizeof(float) * N * DFEAT);
  float* B = (float*)alloc(sizeof(float) * N * DFEAT);
  float* C = (float*)alloc(sizeof(float) * N * DFEAT);
  // aliases into C (dead before layer0's k_gemm writes C):
  unsigned* pairs = (unsigned*)C;                          // 4B * E = 6.4MB
  unsigned char* sloc = (unsigned char*)C + (16u << 20);   // 1B * E at +16MB
  (void)ws_size; (void)n_in; (void)out_size;

  k_zero_i32<<<4, 256, 0, stream>>>(cnts, 2 * NB_MAX);
  k_hist<<<512, 256, 0, stream>>>(src, dst, dst_cnt, src_cnt, E, NB);
  k_scan2<<<1, NB_MAX, 0, stream>>>(dst_cnt, src_cnt, dst_base, src_base,
                                    dst_cur, src_cur, NB, E);
  k_partition<<<PART_BLOCKS, 256, 0, stream>>>(src, dst, dst_cur, src_cur,
                                               pairs, sloc, E, NB);
  k_build_dst<<<NB, BSZ, 0, stream>>>(pairs, dst_base, row_off, ndst, csr_src, N, E);
  k_build_src<<<NB, BSZ, 0, stream>>>(sloc, src_base, nsrc, N);
  k_prescale<<<2048, 256, 0, stream>>>(x, nsrc, A, N * (DFEAT / 4));

  // 3-buffer chain (gemm strictly out-of-place for SMEM noclobber):
  // L0: agg A->B, gemm B->C ; L1: agg C->B, gemm B->A ; L2: agg A->B, gemm B->out
  for (int l = 0; l < L; l++) {
    const float* hin = (l == 0) ? A : ((l == 1) ? C : A);
    float* G = B;
    float* ho = (l == L - 1) ? out : ((l == 0) ? C : A);
    k_agg<<<2048, 256, 0, stream>>>(hin, ndst, row_off, csr_src, G, N);
    k_gemm<<<2048, 256, 0, stream>>>(G, nsrc, Ws + l * DFEAT * DFEAT,
                                     bs + l * DFEAT, ho, N, l != L - 1);
  }
}

// Round 12
// 387.696 us; speedup vs baseline: 5.7472x; 1.1572x over previous
//
#include <hip/hip_runtime.h>
#include <math.h>

#define DFEAT 64
#define BUCKET_SHIFT 8          // 256 nodes per bucket
#define BSZ (1 << BUCKET_SHIFT)
#define NB_MAX 512              // supports N <= 131072
#define PART_BLOCKS 192

typedef __attribute__((ext_vector_type(4))) _Float16 half4;

static inline int imin(int a, int b) { return a < b ? a : b; }

// ---------------- preprocessing ----------------

__global__ void k_zero_i32(int* __restrict__ p, int n) {
  int i = blockIdx.x * blockDim.x + threadIdx.x;
  int stride = gridDim.x * blockDim.x;
  for (; i < n; i += stride) p[i] = 0;
}

// bucket histograms for dst and src (LDS-only per-edge atomics)
__global__ void __launch_bounds__(256) k_hist(
    const int* __restrict__ src, const int* __restrict__ dst,
    int* __restrict__ dst_cnt, int* __restrict__ src_cnt, int E, int NB) {
  __shared__ int hd[NB_MAX], hs[NB_MAX];
  for (int b = threadIdx.x; b < NB; b += blockDim.x) { hd[b] = 0; hs[b] = 0; }
  __syncthreads();
  int i = blockIdx.x * blockDim.x + threadIdx.x;
  int stride = gridDim.x * blockDim.x;
  for (; i < E; i += stride) {
    atomicAdd(&hd[dst[i] >> BUCKET_SHIFT], 1);
    atomicAdd(&hs[src[i] >> BUCKET_SHIFT], 1);
  }
  __syncthreads();
  for (int b = threadIdx.x; b < NB; b += blockDim.x) {
    if (hd[b]) atomicAdd(&dst_cnt[b], hd[b]);
    if (hs[b]) atomicAdd(&src_cnt[b], hs[b]);
  }
}

// exclusive scans of both bucket-count arrays -> base (NB+1) and live cursors
__global__ void k_scan2(const int* __restrict__ dst_cnt, const int* __restrict__ src_cnt,
                        int* __restrict__ dst_base, int* __restrict__ src_base,
                        int* __restrict__ dst_cur, int* __restrict__ src_cur,
                        int NB, int E) {
  __shared__ int sh[NB_MAX];
  int t = threadIdx.x;
  int v = (t < NB) ? dst_cnt[t] : 0;
  sh[t] = v;
  __syncthreads();
  for (int o = 1; o < NB_MAX; o <<= 1) {
    int x = (t >= o) ? sh[t - o] : 0;
    __syncthreads();
    sh[t] += x;
    __syncthreads();
  }
  if (t < NB) { dst_base[t] = sh[t] - v; dst_cur[t] = sh[t] - v; }
  if (t == 0) dst_base[NB] = E;
  __syncthreads();
  int v2 = (t < NB) ? src_cnt[t] : 0;
  sh[t] = v2;
  __syncthreads();
  for (int o = 1; o < NB_MAX; o <<= 1) {
    int x = (t >= o) ? sh[t - o] : 0;
    __syncthreads();
    sh[t] += x;
    __syncthreads();
  }
  if (t < NB) { src_base[t] = sh[t] - v2; src_cur[t] = sh[t] - v2; }
  if (t == 0) src_base[NB] = E;
}

// coarse partition: (dloc<<24|src) pairs grouped by dst bucket + 1B/edge
// src-local stream grouped by src bucket.
__global__ void __launch_bounds__(256) k_partition(
    const int* __restrict__ src, const int* __restrict__ dst,
    int* __restrict__ dst_cur, int* __restrict__ src_cur,
    unsigned* __restrict__ pairs, unsigned char* __restrict__ sloc, int E, int NB) {
  __shared__ int cd[NB_MAX], cs[NB_MAX];
  const int per = (E + gridDim.x - 1) / gridDim.x;
  int e0 = blockIdx.x * per;
  int e1 = e0 + per; if (e1 > E) e1 = E;
  for (int b = threadIdx.x; b < NB; b += blockDim.x) { cd[b] = 0; cs[b] = 0; }
  __syncthreads();
  for (int i = e0 + threadIdx.x; i < e1; i += blockDim.x) {
    atomicAdd(&cd[dst[i] >> BUCKET_SHIFT], 1);
    atomicAdd(&cs[src[i] >> BUCKET_SHIFT], 1);
  }
  __syncthreads();
  for (int b = threadIdx.x; b < NB; b += blockDim.x) {
    int c = cd[b]; cd[b] = c ? atomicAdd(&dst_cur[b], c) : 0;
    int c2 = cs[b]; cs[b] = c2 ? atomicAdd(&src_cur[b], c2) : 0;
  }
  __syncthreads();
  for (int i = e0 + threadIdx.x; i < e1; i += blockDim.x) {
    int d = dst[i], s = src[i];
    int p = atomicAdd(&cd[d >> BUCKET_SHIFT], 1);
    pairs[p] = ((unsigned)(d & (BSZ - 1)) << 24) | (unsigned)s;
    int q = atomicAdd(&cs[s >> BUCKET_SHIFT], 1);
    sloc[q] = (unsigned char)(s & (BSZ - 1));
  }
}

// one block per dst bucket: LDS in-degree count + scan -> row_off, ndst, csr fill
__global__ void __launch_bounds__(256) k_build_dst(
    const unsigned* __restrict__ pairs, const int* __restrict__ dst_base,
    int* __restrict__ row_off, float* __restrict__ ndst, int* __restrict__ csr_src,
    int N, int E) {
  __shared__ int cnt[BSZ];
  __shared__ int pos[BSZ];
  int b = blockIdx.x, t = threadIdx.x;
  int s0 = dst_base[b], s1 = dst_base[b + 1];
  cnt[t] = 0;
  __syncthreads();
  for (int i = s0 + t; i < s1; i += BSZ) atomicAdd(&cnt[pairs[i] >> 24], 1);
  __syncthreads();
  int c = cnt[t];
  pos[t] = c;
  __syncthreads();
  for (int o = 1; o < BSZ; o <<= 1) {
    int x = (t >= o) ? pos[t - o] : 0;
    __syncthreads();
    pos[t] += x;
    __syncthreads();
  }
  int excl = pos[t] - c;
  int node = (b << BUCKET_SHIFT) + t;
  if (node < N) {
    row_off[node] = s0 + excl;
    ndst[node] = c > 0 ? rsqrtf((float)c) : 0.0f;
  }
  __syncthreads();
  pos[t] = excl;  // live cursors
  __syncthreads();
  for (int i = s0 + t; i < s1; i += BSZ) {
    unsigned pr = pairs[i];
    int p = atomicAdd(&pos[pr >> 24], 1);
    csr_src[s0 + p] = (int)(pr & 0xFFFFFFu);
  }
  if (b == 0 && t == 0) row_off[N] = E;
}

// one block per src bucket: LDS out-degree count -> nsrc (dense write)
__global__ void __launch_bounds__(256) k_build_src(
    const unsigned char* __restrict__ sloc, const int* __restrict__ src_base,
    float* __restrict__ nsrc, int N) {
  __shared__ int cnt[BSZ];
  int b = blockIdx.x, t = threadIdx.x;
  int s0 = src_base[b], s1 = src_base[b + 1];
  cnt[t] = 0;
  __syncthreads();
  for (int i = s0 + t; i < s1; i += BSZ) atomicAdd(&cnt[sloc[i]], 1);
  __syncthreads();
  int node = (b << BUCKET_SHIFT) + t;
  if (node < N) nsrc[node] = cnt[t] > 0 ? rsqrtf((float)cnt[t]) : 0.0f;
}

// A[i] = fp16( x[i] * nsrc[row] )   (nq = N*16 quads)
__global__ void __launch_bounds__(256) k_prescale(const float* __restrict__ x,
                                                  const float* __restrict__ nsrc,
                                                  _Float16* __restrict__ A, int nq) {
  int i = blockIdx.x * blockDim.x + threadIdx.x;
  int stride = gridDim.x * blockDim.x;
  for (; i < nq; i += stride) {
    int row = i >> 4;
    float4 v = ((const float4*)x)[i];
    float s = nsrc[row];
    half4 h;
    h.x = (_Float16)(v.x * s); h.y = (_Float16)(v.y * s);
    h.z = (_Float16)(v.z * s); h.w = (_Float16)(v.w * s);
    ((half4*)A)[i] = h;
  }
}

// ---------------- aggregation kernel (pure gather, fp16 input) ----------------
// One row per wave; 4 edge slots x 16 feat-quads; 4 half4 (8B) loads in flight
// per lane; fp32 accumulate. Output agg[r] (fp32) = ndst[r] * sum hin[src_e].
__global__ void __launch_bounds__(256) k_agg(
    const _Float16* __restrict__ hin, const float* __restrict__ ndst,
    const int* __restrict__ row_off, const int* __restrict__ csr_src,
    float* __restrict__ agg, int n) {
  const int lane = threadIdx.x & 63;
  const int f4 = (lane & 15) * 4;  // feature offset of this lane's quad
  const int e = lane >> 4;         // edge slot 0..3

  int wid = blockIdx.x * (blockDim.x >> 6) + (threadIdx.x >> 6);
  int nw = gridDim.x * (blockDim.x >> 6);

  for (int r = wid; r < n; r += nw) {
    int beg = row_off[r], end = row_off[r + 1];
    float sx0 = 0, sy0 = 0, sz0 = 0, sw0 = 0;
    float sx1 = 0, sy1 = 0, sz1 = 0, sw1 = 0;
    float sx2 = 0, sy2 = 0, sz2 = 0, sw2 = 0;
    float sx3 = 0, sy3 = 0, sz3 = 0, sw3 = 0;
    int k = beg + e;
    for (; k + 12 < end; k += 16) {
      int sA = csr_src[k];
      int sB = csr_src[k + 4];
      int sC = csr_src[k + 8];
      int sD = csr_src[k + 12];
      const half4 vA = *(const half4*)(hin + sA * DFEAT + f4);
      const half4 vB = *(const half4*)(hin + sB * DFEAT + f4);
      const half4 vC = *(const half4*)(hin + sC * DFEAT + f4);
      const half4 vD = *(const half4*)(hin + sD * DFEAT + f4);
      sx0 += (float)vA.x; sy0 += (float)vA.y; sz0 += (float)vA.z; sw0 += (float)vA.w;
      sx1 += (float)vB.x; sy1 += (float)vB.y; sz1 += (float)vB.z; sw1 += (float)vB.w;
      sx2 += (float)vC.x; sy2 += (float)vC.y; sz2 += (float)vC.z; sw2 += (float)vC.w;
      sx3 += (float)vD.x; sy3 += (float)vD.y; sz3 += (float)vD.z; sw3 += (float)vD.w;
    }
    for (; k < end; k += 4) {
      int sA = csr_src[k];
      const half4 vA = *(const half4*)(hin + sA * DFEAT + f4);
      sx0 += (float)vA.x; sy0 += (float)vA.y; sz0 += (float)vA.z; sw0 += (float)vA.w;
    }
    float sx = (sx0 + sx1) + (sx2 + sx3);
    float sy = (sy0 + sy1) + (sy2 + sy3);
    float sz = (sz0 + sz1) + (sz2 + sz3);
    float sw = (sw0 + sw1) + (sw2 + sw3);
    // reduce across the 4 edge slots
    sx += __shfl_xor(sx, 16); sy += __shfl_xor(sy, 16);
    sz += __shfl_xor(sz, 16); sw += __shfl_xor(sw, 16);
    sx += __shfl_xor(sx, 32); sy += __shfl_xor(sy, 32);
    sz += __shfl_xor(sz, 32); sw += __shfl_xor(sw, 32);

    float nd = ndst[r];
    if (e == 0) {
      float4 v = make_float4(sx * nd, sy * nd, sz * nd, sw * nd);
      *(float4*)(agg + r * DFEAT + f4) = v;
    }
  }
}

// ---------------- dense GEMM + relu kernels ----------------
// Row values are wave-uniform scalars via readfirstlane + __restrict__
// out-of-place -> s_load path; W column in VGPRs; inner loop = 64 s-operand FMA.

// variant writing fp16 h for the next layer (folds nsrc)
__global__ void __launch_bounds__(256) k_gemm_h(
    const float* __restrict__ agg, const float* __restrict__ nsrc,
    const float* __restrict__ W, const float* __restrict__ b,
    _Float16* __restrict__ out, int n) {
  const int lane = threadIdx.x & 63;
  float wreg[DFEAT];
#pragma unroll
  for (int k = 0; k < DFEAT; k++) wreg[k] = W[k * DFEAT + lane];
  const float bias = b[lane];
  int wid = blockIdx.x * (blockDim.x >> 6) + (threadIdx.x >> 6);
  int nw = gridDim.x * (blockDim.x >> 6);
  for (int r = wid; r < n; r += nw) {
    int ru = __builtin_amdgcn_readfirstlane(r);
    const float* __restrict__ rowp = agg + (size_t)ru * DFEAT;
    float a0 = bias, a1 = 0.0f, a2 = 0.0f, a3 = 0.0f;
#pragma unroll
    for (int q = 0; q < DFEAT; q += 4) {
      a0 = fmaf(rowp[q + 0], wreg[q + 0], a0);
      a1 = fmaf(rowp[q + 1], wreg[q + 1], a1);
      a2 = fmaf(rowp[q + 2], wreg[q + 2], a2);
      a3 = fmaf(rowp[q + 3], wreg[q + 3], a3);
    }
    float acc = (a0 + a1) + (a2 + a3);
    acc = fmaxf(acc, 0.0f) * nsrc[ru];
    out[(size_t)ru * DFEAT + lane] = (_Float16)acc;
  }
}

// variant writing fp32 (final layer -> d_out, no nsrc fold)
__global__ void __launch_bounds__(256) k_gemm_f(
    const float* __restrict__ agg,
    const float* __restrict__ W, const float* __restrict__ b,
    float* __restrict__ out, int n) {
  const int lane = threadIdx.x & 63;
  float wreg[DFEAT];
#pragma unroll
  for (int k = 0; k < DFEAT; k++) wreg[k] = W[k * DFEAT + lane];
  const float bias = b[lane];
  int wid = blockIdx.x * (blockDim.x >> 6) + (threadIdx.x >> 6);
  int nw = gridDim.x * (blockDim.x >> 6);
  for (int r = wid; r < n; r += nw) {
    int ru = __builtin_amdgcn_readfirstlane(r);
    const float* __restrict__ rowp = agg + (size_t)ru * DFEAT;
    float a0 = bias, a1 = 0.0f, a2 = 0.0f, a3 = 0.0f;
#pragma unroll
    for (int q = 0; q < DFEAT; q += 4) {
      a0 = fmaf(rowp[q + 0], wreg[q + 0], a0);
      a1 = fmaf(rowp[q + 1], wreg[q + 1], a1);
      a2 = fmaf(rowp[q + 2], wreg[q + 2], a2);
      a3 = fmaf(rowp[q + 3], wreg[q + 3], a3);
    }
    float acc = (a0 + a1) + (a2 + a3);
    acc = fmaxf(acc, 0.0f);
    out[(size_t)ru * DFEAT + lane] = acc;
  }
}

// ---------------- launch ----------------

extern "C" void kernel_launch(void* const* d_in, const int* in_sizes, int n_in,
                              void* d_out, int out_size, void* d_ws, size_t ws_size,
                              hipStream_t stream) {
  const float* x = (const float*)d_in[0];
  const int* ei = (const int*)d_in[1];
  const float* Ws = (const float*)d_in[2];
  const float* bs = (const float*)d_in[3];
  float* out = (float*)d_out;

  const int N = in_sizes[0] / DFEAT;
  const int E = in_sizes[1] / 2;
  const int L = in_sizes[2] / (DFEAT * DFEAT);
  const int* src = ei;
  const int* dst = ei + E;
  const int NB = (N + BSZ - 1) >> BUCKET_SHIFT;  // 391 for N=100K

  // workspace carve-up (256B-aligned)
  char* w = (char*)d_ws;
  auto alloc = [&](size_t bytes) -> void* {
    void* p = (void*)w;
    w += (bytes + 255) & ~(size_t)255;
    return p;
  };
  int* cnts = (int*)alloc(sizeof(int) * 2 * NB_MAX);       // dst_cnt | src_cnt
  int* dst_cnt = cnts;
  int* src_cnt = cnts + NB_MAX;
  int* dst_base = (int*)alloc(sizeof(int) * (NB_MAX + 1));
  int* src_base = (int*)alloc(sizeof(int) * (NB_MAX + 1));
  int* dst_cur = (int*)alloc(sizeof(int) * NB_MAX);
  int* src_cur = (int*)alloc(sizeof(int) * NB_MAX);
  float* nsrc = (float*)alloc(sizeof(float) * N);
  float* ndst = (float*)alloc(sizeof(float) * N);
  int* row_off = (int*)alloc(sizeof(int) * (N + 1));
  int* csr_src = (int*)alloc(sizeof(int) * E);
  _Float16* A = (_Float16*)alloc(sizeof(_Float16) * N * DFEAT);  // h buffers: fp16
  _Float16* C = (_Float16*)alloc(sizeof(_Float16) * N * DFEAT);
  float* B = (float*)alloc(sizeof(float) * N * DFEAT);           // agg buffer: fp32
  // aliases into B (dead until layer0's k_agg writes it; 25.6MB total):
  unsigned* pairs = (unsigned*)B;                          // 4B * E = 6.4MB
  unsigned char* sloc = (unsigned char*)B + (12u << 20);   // 1B * E at +12MB
  (void)ws_size; (void)n_in; (void)out_size;

  k_zero_i32<<<4, 256, 0, stream>>>(cnts, 2 * NB_MAX);
  k_hist<<<512, 256, 0, stream>>>(src, dst, dst_cnt, src_cnt, E, NB);
  k_scan2<<<1, NB_MAX, 0, stream>>>(dst_cnt, src_cnt, dst_base, src_base,
                                    dst_cur, src_cur, NB, E);
  k_partition<<<PART_BLOCKS, 256, 0, stream>>>(src, dst, dst_cur, src_cur,
                                               pairs, sloc, E, NB);
  k_build_dst<<<NB, BSZ, 0, stream>>>(pairs, dst_base, row_off, ndst, csr_src, N, E);
  k_build_src<<<NB, BSZ, 0, stream>>>(sloc, src_base, nsrc, N);
  k_prescale<<<2048, 256, 0, stream>>>(x, nsrc, A, N * (DFEAT / 4));

  // L0: agg A->B, gemm_h B->C ; L1: agg C->B, gemm_h B->A ; L2: agg A->B, gemm_f B->out
  for (int l = 0; l < L; l++) {
    const _Float16* hin = (l == 1) ? C : A;
    k_agg<<<2048, 256, 0, stream>>>(hin, ndst, row_off, csr_src, B, N);
    if (l == L - 1) {
      k_gemm_f<<<2048, 256, 0, stream>>>(B, Ws + l * DFEAT * DFEAT,
                                         bs + l * DFEAT, out, N);
    } else {
      _Float16* ho = (l == 0) ? C : A;
      k_gemm_h<<<2048, 256, 0, stream>>>(B, nsrc, Ws + l * DFEAT * DFEAT,
                                         bs + l * DFEAT, ho, N);
    }
  }
}

// Round 13
// 381.516 us; speedup vs baseline: 5.8402x; 1.0162x over previous
//
#include <hip/hip_runtime.h>
#include <math.h>

#define DFEAT 64
#define BUCKET_SHIFT 8          // 256 nodes per bucket
#define BSZ (1 << BUCKET_SHIFT)
#define NB_MAX 512              // supports N <= 131072
#define PART_BLOCKS 256

typedef __attribute__((ext_vector_type(4))) _Float16 half4;

static inline int imin(int a, int b) { return a < b ? a : b; }

// ---------------- preprocessing ----------------

__global__ void k_zero_i32(int* __restrict__ p, int n) {
  int i = blockIdx.x * blockDim.x + threadIdx.x;
  int stride = gridDim.x * blockDim.x;
  for (; i < n; i += stride) p[i] = 0;
}

// bucket histograms for dst and src (LDS-only per-edge atomics)
__global__ void __launch_bounds__(256) k_hist(
    const int* __restrict__ src, const int* __restrict__ dst,
    int* __restrict__ dst_cnt, int* __restrict__ src_cnt, int E, int NB) {
  __shared__ int hd[NB_MAX], hs[NB_MAX];
  for (int b = threadIdx.x; b < NB; b += blockDim.x) { hd[b] = 0; hs[b] = 0; }
  __syncthreads();
  int i = blockIdx.x * blockDim.x + threadIdx.x;
  int stride = gridDim.x * blockDim.x;
  for (; i < E; i += stride) {
    atomicAdd(&hd[dst[i] >> BUCKET_SHIFT], 1);
    atomicAdd(&hs[src[i] >> BUCKET_SHIFT], 1);
  }
  __syncthreads();
  for (int b = threadIdx.x; b < NB; b += blockDim.x) {
    if (hd[b]) atomicAdd(&dst_cnt[b], hd[b]);
    if (hs[b]) atomicAdd(&src_cnt[b], hs[b]);
  }
}

// exclusive scans of both bucket-count arrays -> base (NB+1) and live cursors
__global__ void k_scan2(const int* __restrict__ dst_cnt, const int* __restrict__ src_cnt,
                        int* __restrict__ dst_base, int* __restrict__ src_base,
                        int* __restrict__ dst_cur, int* __restrict__ src_cur,
                        int NB, int E) {
  __shared__ int sh[NB_MAX];
  int t = threadIdx.x;
  int v = (t < NB) ? dst_cnt[t] : 0;
  sh[t] = v;
  __syncthreads();
  for (int o = 1; o < NB_MAX; o <<= 1) {
    int x = (t >= o) ? sh[t - o] : 0;
    __syncthreads();
    sh[t] += x;
    __syncthreads();
  }
  if (t < NB) { dst_base[t] = sh[t] - v; dst_cur[t] = sh[t] - v; }
  if (t == 0) dst_base[NB] = E;
  __syncthreads();
  int v2 = (t < NB) ? src_cnt[t] : 0;
  sh[t] = v2;
  __syncthreads();
  for (int o = 1; o < NB_MAX; o <<= 1) {
    int x = (t >= o) ? sh[t - o] : 0;
    __syncthreads();
    sh[t] += x;
    __syncthreads();
  }
  if (t < NB) { src_base[t] = sh[t] - v2; src_cur[t] = sh[t] - v2; }
  if (t == 0) src_base[NB] = E;
}

// coarse partition: (dloc<<24|src) pairs grouped by dst bucket + 1B/edge
// src-local stream grouped by src bucket.
__global__ void __launch_bounds__(256) k_partition(
    const int* __restrict__ src, const int* __restrict__ dst,
    int* __restrict__ dst_cur, int* __restrict__ src_cur,
    unsigned* __restrict__ pairs, unsigned char* __restrict__ sloc, int E, int NB) {
  __shared__ int cd[NB_MAX], cs[NB_MAX];
  const int per = (E + gridDim.x - 1) / gridDim.x;
  int e0 = blockIdx.x * per;
  int e1 = e0 + per; if (e1 > E) e1 = E;
  for (int b = threadIdx.x; b < NB; b += blockDim.x) { cd[b] = 0; cs[b] = 0; }
  __syncthreads();
  for (int i = e0 + threadIdx.x; i < e1; i += blockDim.x) {
    atomicAdd(&cd[dst[i] >> BUCKET_SHIFT], 1);
    atomicAdd(&cs[src[i] >> BUCKET_SHIFT], 1);
  }
  __syncthreads();
  for (int b = threadIdx.x; b < NB; b += blockDim.x) {
    int c = cd[b]; cd[b] = c ? atomicAdd(&dst_cur[b], c) : 0;
    int c2 = cs[b]; cs[b] = c2 ? atomicAdd(&src_cur[b], c2) : 0;
  }
  __syncthreads();
  for (int i = e0 + threadIdx.x; i < e1; i += blockDim.x) {
    int d = dst[i], s = src[i];
    int p = atomicAdd(&cd[d >> BUCKET_SHIFT], 1);
    pairs[p] = ((unsigned)(d & (BSZ - 1)) << 24) | (unsigned)s;
    int q = atomicAdd(&cs[s >> BUCKET_SHIFT], 1);
    sloc[q] = (unsigned char)(s & (BSZ - 1));
  }
}

// one block per dst bucket: LDS in-degree count + scan -> row_off, ndst, csr fill
__global__ void __launch_bounds__(256) k_build_dst(
    const unsigned* __restrict__ pairs, const int* __restrict__ dst_base,
    int* __restrict__ row_off, float* __restrict__ ndst, int* __restrict__ csr_src,
    int N, int E) {
  __shared__ int cnt[BSZ];
  __shared__ int pos[BSZ];
  int b = blockIdx.x, t = threadIdx.x;
  int s0 = dst_base[b], s1 = dst_base[b + 1];
  cnt[t] = 0;
  __syncthreads();
  for (int i = s0 + t; i < s1; i += BSZ) atomicAdd(&cnt[pairs[i] >> 24], 1);
  __syncthreads();
  int c = cnt[t];
  pos[t] = c;
  __syncthreads();
  for (int o = 1; o < BSZ; o <<= 1) {
    int x = (t >= o) ? pos[t - o] : 0;
    __syncthreads();
    pos[t] += x;
    __syncthreads();
  }
  int excl = pos[t] - c;
  int node = (b << BUCKET_SHIFT) + t;
  if (node < N) {
    row_off[node] = s0 + excl;
    ndst[node] = c > 0 ? rsqrtf((float)c) : 0.0f;
  }
  __syncthreads();
  pos[t] = excl;  // live cursors
  __syncthreads();
  for (int i = s0 + t; i < s1; i += BSZ) {
    unsigned pr = pairs[i];
    int p = atomicAdd(&pos[pr >> 24], 1);
    csr_src[s0 + p] = (int)(pr & 0xFFFFFFu);
  }
  if (b == 0 && t == 0) row_off[N] = E;
}

// one block per src bucket: LDS out-degree count -> nsrc (dense write)
__global__ void __launch_bounds__(256) k_build_src(
    const unsigned char* __restrict__ sloc, const int* __restrict__ src_base,
    float* __restrict__ nsrc, int N) {
  __shared__ int cnt[BSZ];
  int b = blockIdx.x, t = threadIdx.x;
  int s0 = src_base[b], s1 = src_base[b + 1];
  cnt[t] = 0;
  __syncthreads();
  for (int i = s0 + t; i < s1; i += BSZ) atomicAdd(&cnt[sloc[i]], 1);
  __syncthreads();
  int node = (b << BUCKET_SHIFT) + t;
  if (node < N) nsrc[node] = cnt[t] > 0 ? rsqrtf((float)cnt[t]) : 0.0f;
}

// A[i] = fp16( x[i] * nsrc[row] )   (nq = N*16 quads)
__global__ void __launch_bounds__(256) k_prescale(const float* __restrict__ x,
                                                  const float* __restrict__ nsrc,
                                                  _Float16* __restrict__ A, int nq) {
  int i = blockIdx.x * blockDim.x + threadIdx.x;
  int stride = gridDim.x * blockDim.x;
  for (; i < nq; i += stride) {
    int row = i >> 4;
    float4 v = ((const float4*)x)[i];
    float s = nsrc[row];
    half4 h;
    h.x = (_Float16)(v.x * s); h.y = (_Float16)(v.y * s);
    h.z = (_Float16)(v.z * s); h.w = (_Float16)(v.w * s);
    ((half4*)A)[i] = h;
  }
}

// ---------------- aggregation kernel (pure gather, fp16 input) ----------------
// TWO adjacent rows per wave, fused loop: both rows' 4-deep gather bursts are
// issued back-to-back (8 loads in flight per lane) so row0's accumulate waits
// with row1's loads still outstanding -> ~2x memory-level parallelism vs the
// one-row version, and the shuffle-reduce drain amortizes over 2 rows.
// Per row: 4 edge slots x 16 feat-quads, fp32 accumulate.
__global__ void __launch_bounds__(256) k_agg(
    const _Float16* __restrict__ hin, const float* __restrict__ ndst,
    const int* __restrict__ row_off, const int* __restrict__ csr_src,
    float* __restrict__ agg, int n) {
  const int lane = threadIdx.x & 63;
  const int f4 = (lane & 15) * 4;  // feature offset of this lane's quad
  const int e = lane >> 4;         // edge slot 0..3

  int wid = blockIdx.x * (blockDim.x >> 6) + (threadIdx.x >> 6);
  int nw = gridDim.x * (blockDim.x >> 6);

  for (int rp = wid * 2; rp < n; rp += nw * 2) {
    const int r0 = rp;
    const int r1 = rp + 1;
    const bool has1 = r1 < n;
    int beg0 = row_off[r0], end0 = row_off[r0 + 1];
    int beg1 = has1 ? row_off[r1] : 0;
    int end1 = has1 ? row_off[r1 + 1] : 0;

    // two independent accumulator chains per component per row
    float x00 = 0, y00 = 0, z00 = 0, w00 = 0, x01 = 0, y01 = 0, z01 = 0, w01 = 0;
    float x10 = 0, y10 = 0, z10 = 0, w10 = 0, x11 = 0, y11 = 0, z11 = 0, w11 = 0;

    int k0 = beg0 + e;
    int k1 = beg1 + e;
    bool a0 = (k0 + 12 < end0);
    bool a1 = (k1 + 12 < end1);
    while (a0 || a1) {
      half4 vA, vB, vC, vD, uA, uB, uC, uD;
      if (a0) {
        int sA = csr_src[k0], sB = csr_src[k0 + 4];
        int sC = csr_src[k0 + 8], sD = csr_src[k0 + 12];
        vA = *(const half4*)(hin + sA * DFEAT + f4);
        vB = *(const half4*)(hin + sB * DFEAT + f4);
        vC = *(const half4*)(hin + sC * DFEAT + f4);
        vD = *(const half4*)(hin + sD * DFEAT + f4);
      }
      if (a1) {
        int tA = csr_src[k1], tB = csr_src[k1 + 4];
        int tC = csr_src[k1 + 8], tD = csr_src[k1 + 12];
        uA = *(const half4*)(hin + tA * DFEAT + f4);
        uB = *(const half4*)(hin + tB * DFEAT + f4);
        uC = *(const half4*)(hin + tC * DFEAT + f4);
        uD = *(const half4*)(hin + tD * DFEAT + f4);
      }
      if (a0) {
        x00 += (float)vA.x + (float)vB.x; y00 += (float)vA.y + (float)vB.y;
        z00 += (float)vA.z + (float)vB.z; w00 += (float)vA.w + (float)vB.w;
        x01 += (float)vC.x + (float)vD.x; y01 += (float)vC.y + (float)vD.y;
        z01 += (float)vC.z + (float)vD.z; w01 += (float)vC.w + (float)vD.w;
        k0 += 16;
      }
      if (a1) {
        x10 += (float)uA.x + (float)uB.x; y10 += (float)uA.y + (float)uB.y;
        z10 += (float)uA.z + (float)uB.z; w10 += (float)uA.w + (float)uB.w;
        x11 += (float)uC.x + (float)uD.x; y11 += (float)uC.y + (float)uD.y;
        z11 += (float)uC.z + (float)uD.z; w11 += (float)uC.w + (float)uD.w;
        k1 += 16;
      }
      a0 = (k0 + 12 < end0);
      a1 = (k1 + 12 < end1);
    }
    // tails (0..3 four-edge steps each; per-lane masking on k<end)
    for (; k0 < end0; k0 += 4) {
      int sA = csr_src[k0];
      const half4 vA = *(const half4*)(hin + sA * DFEAT + f4);
      x00 += (float)vA.x; y00 += (float)vA.y; z00 += (float)vA.z; w00 += (float)vA.w;
    }
    for (; k1 < end1; k1 += 4) {
      int tA = csr_src[k1];
      const half4 uA = *(const half4*)(hin + tA * DFEAT + f4);
      x10 += (float)uA.x; y10 += (float)uA.y; z10 += (float)uA.z; w10 += (float)uA.w;
    }

    // reduce + store row0
    float sx = x00 + x01, sy = y00 + y01, sz = z00 + z01, sw = w00 + w01;
    sx += __shfl_xor(sx, 16); sy += __shfl_xor(sy, 16);
    sz += __shfl_xor(sz, 16); sw += __shfl_xor(sw, 16);
    sx += __shfl_xor(sx, 32); sy += __shfl_xor(sy, 32);
    sz += __shfl_xor(sz, 32); sw += __shfl_xor(sw, 32);
    if (e == 0) {
      float nd = ndst[r0];
      *(float4*)(agg + (size_t)r0 * DFEAT + f4) =
          make_float4(sx * nd, sy * nd, sz * nd, sw * nd);
    }
    // reduce + store row1
    if (has1) {
      float tx = x10 + x11, ty = y10 + y11, tz = z10 + z11, tw = w10 + w11;
      tx += __shfl_xor(tx, 16); ty += __shfl_xor(ty, 16);
      tz += __shfl_xor(tz, 16); tw += __shfl_xor(tw, 16);
      tx += __shfl_xor(tx, 32); ty += __shfl_xor(ty, 32);
      tz += __shfl_xor(tz, 32); tw += __shfl_xor(tw, 32);
      if (e == 0) {
        float nd = ndst[r1];
        *(float4*)(agg + (size_t)r1 * DFEAT + f4) =
            make_float4(tx * nd, ty * nd, tz * nd, tw * nd);
      }
    }
  }
}

// ---------------- dense GEMM + relu kernels ----------------
// Row values are wave-uniform scalars via readfirstlane + __restrict__
// out-of-place -> s_load path; W column in VGPRs; inner loop = 64 s-operand FMA.

// variant writing fp16 h for the next layer (folds nsrc)
__global__ void __launch_bounds__(256) k_gemm_h(
    const float* __restrict__ agg, const float* __restrict__ nsrc,
    const float* __restrict__ W, const float* __restrict__ b,
    _Float16* __restrict__ out, int n) {
  const int lane = threadIdx.x & 63;
  float wreg[DFEAT];
#pragma unroll
  for (int k = 0; k < DFEAT; k++) wreg[k] = W[k * DFEAT + lane];
  const float bias = b[lane];
  int wid = blockIdx.x * (blockDim.x >> 6) + (threadIdx.x >> 6);
  int nw = gridDim.x * (blockDim.x >> 6);
  for (int r = wid; r < n; r += nw) {
    int ru = __builtin_amdgcn_readfirstlane(r);
    const float* __restrict__ rowp = agg + (size_t)ru * DFEAT;
    float a0 = bias, a1 = 0.0f, a2 = 0.0f, a3 = 0.0f;
#pragma unroll
    for (int q = 0; q < DFEAT; q += 4) {
      a0 = fmaf(rowp[q + 0], wreg[q + 0], a0);
      a1 = fmaf(rowp[q + 1], wreg[q + 1], a1);
      a2 = fmaf(rowp[q + 2], wreg[q + 2], a2);
      a3 = fmaf(rowp[q + 3], wreg[q + 3], a3);
    }
    float acc = (a0 + a1) + (a2 + a3);
    acc = fmaxf(acc, 0.0f) * nsrc[ru];
    out[(size_t)ru * DFEAT + lane] = (_Float16)acc;
  }
}

// variant writing fp32 (final layer -> d_out, no nsrc fold)
__global__ void __launch_bounds__(256) k_gemm_f(
    const float* __restrict__ agg,
    const float* __restrict__ W, const float* __restrict__ b,
    float* __restrict__ out, int n) {
  const int lane = threadIdx.x & 63;
  float wreg[DFEAT];
#pragma unroll
  for (int k = 0; k < DFEAT; k++) wreg[k] = W[k * DFEAT + lane];
  const float bias = b[lane];
  int wid = blockIdx.x * (blockDim.x >> 6) + (threadIdx.x >> 6);
  int nw = gridDim.x * (blockDim.x >> 6);
  for (int r = wid; r < n; r += nw) {
    int ru = __builtin_amdgcn_readfirstlane(r);
    const float* __restrict__ rowp = agg + (size_t)ru * DFEAT;
    float a0 = bias, a1 = 0.0f, a2 = 0.0f, a3 = 0.0f;
#pragma unroll
    for (int q = 0; q < DFEAT; q += 4) {
      a0 = fmaf(rowp[q + 0], wreg[q + 0], a0);
      a1 = fmaf(rowp[q + 1], wreg[q + 1], a1);
      a2 = fmaf(rowp[q + 2], wreg[q + 2], a2);
      a3 = fmaf(rowp[q + 3], wreg[q + 3], a3);
    }
    float acc = (a0 + a1) + (a2 + a3);
    acc = fmaxf(acc, 0.0f);
    out[(size_t)ru * DFEAT + lane] = acc;
  }
}

// ---------------- launch ----------------

extern "C" void kernel_launch(void* const* d_in, const int* in_sizes, int n_in,
                              void* d_out, int out_size, void* d_ws, size_t ws_size,
                              hipStream_t stream) {
  const float* x = (const float*)d_in[0];
  const int* ei = (const int*)d_in[1];
  const float* Ws = (const float*)d_in[2];
  const float* bs = (const float*)d_in[3];
  float* out = (float*)d_out;

  const int N = in_sizes[0] / DFEAT;
  const int E = in_sizes[1] / 2;
  const int L = in_sizes[2] / (DFEAT * DFEAT);
  const int* src = ei;
  const int* dst = ei + E;
  const int NB = (N + BSZ - 1) >> BUCKET_SHIFT;  // 391 for N=100K

  // workspace carve-up (256B-aligned)
  char* w = (char*)d_ws;
  auto alloc = [&](size_t bytes) -> void* {
    void* p = (void*)w;
    w += (bytes + 255) & ~(size_t)255;
    return p;
  };
  int* cnts = (int*)alloc(sizeof(int) * 2 * NB_MAX);       // dst_cnt | src_cnt
  int* dst_cnt = cnts;
  int* src_cnt = cnts + NB_MAX;
  int* dst_base = (int*)alloc(sizeof(int) * (NB_MAX + 1));
  int* src_base = (int*)alloc(sizeof(int) * (NB_MAX + 1));
  int* dst_cur = (int*)alloc(sizeof(int) * NB_MAX);
  int* src_cur = (int*)alloc(sizeof(int) * NB_MAX);
  float* nsrc = (float*)alloc(sizeof(float) * N);
  float* ndst = (float*)alloc(sizeof(float) * N);
  int* row_off = (int*)alloc(sizeof(int) * (N + 1));
  int* csr_src = (int*)alloc(sizeof(int) * E);
  _Float16* A = (_Float16*)alloc(sizeof(_Float16) * N * DFEAT);  // h buffers: fp16
  _Float16* C = (_Float16*)alloc(sizeof(_Float16) * N * DFEAT);
  float* B = (float*)alloc(sizeof(float) * N * DFEAT);           // agg buffer: fp32
  // aliases into B (dead until layer0's k_agg writes it; 25.6MB total):
  unsigned* pairs = (unsigned*)B;                          // 4B * E = 6.4MB
  unsigned char* sloc = (unsigned char*)B + (12u << 20);   // 1B * E at +12MB
  (void)ws_size; (void)n_in; (void)out_size;

  k_zero_i32<<<4, 256, 0, stream>>>(cnts, 2 * NB_MAX);
  k_hist<<<512, 256, 0, stream>>>(src, dst, dst_cnt, src_cnt, E, NB);
  k_scan2<<<1, NB_MAX, 0, stream>>>(dst_cnt, src_cnt, dst_base, src_base,
                                    dst_cur, src_cur, NB, E);
  k_partition<<<PART_BLOCKS, 256, 0, stream>>>(src, dst, dst_cur, src_cur,
                                               pairs, sloc, E, NB);
  k_build_dst<<<NB, BSZ, 0, stream>>>(pairs, dst_base, row_off, ndst, csr_src, N, E);
  k_build_src<<<NB, BSZ, 0, stream>>>(sloc, src_base, nsrc, N);
  k_prescale<<<2048, 256, 0, stream>>>(x, nsrc, A, N * (DFEAT / 4));

  // L0: agg A->B, gemm_h B->C ; L1: agg C->B, gemm_h B->A ; L2: agg A->B, gemm_f B->out
  for (int l = 0; l < L; l++) {
    const _Float16* hin = (l == 1) ? C : A;
    k_agg<<<2048, 256, 0, stream>>>(hin, ndst, row_off, csr_src, B, N);
    if (l == L - 1) {
      k_gemm_f<<<2048, 256, 0, stream>>>(B, Ws + l * DFEAT * DFEAT,
                                         bs + l * DFEAT, out, N);
    } else {
      _Float16* ho = (l == 0) ? C : A;
      k_gemm_h<<<2048, 256, 0, stream>>>(B, nsrc, Ws + l * DFEAT * DFEAT,
                                         bs + l * DFEAT, ho, N);
    }
  }
}